// Round 10
// baseline (410.530 us; speedup 1.0000x reference)
//
#include <hip/hip_runtime.h>
#include <math.h>

#define NHEAD 4
#define PCH 16
#define NSLOT 64
#define SLOT_STRIDE 512  // floats per slot (>= 2F for both layers)

typedef __bf16 bf16x8 __attribute__((ext_vector_type(8)));
typedef float f32x4 __attribute__((ext_vector_type(4)));

__device__ __forceinline__ unsigned short f2bf(float f) {
  unsigned int u = __float_as_uint(f);
  u += 0x7FFF + ((u >> 16) & 1);  // round-to-nearest-even
  return (unsigned short)(u >> 16);
}
__device__ __forceinline__ float bf2f(unsigned short s) {
  return __uint_as_float(((unsigned int)s) << 16);
}
__device__ __forceinline__ unsigned int comb2(unsigned int p, unsigned int q,
                                              float a0, float a1) {
  float lo = a0 * bf2f((unsigned short)p) + a1 * bf2f((unsigned short)q);
  float hi = a0 * bf2f((unsigned short)(p >> 16)) + a1 * bf2f((unsigned short)(q >> 16));
  return (unsigned)f2bf(lo) | ((unsigned)f2bf(hi) << 16);
}
__device__ __forceinline__ float fast_tanh(float x) {
  x = fminf(fmaxf(x, -15.f), 15.f);
  float e = __expf(2.f * x);
  return (e - 1.f) / (e + 1.f);
}

// ============ combined: weight transpose+cast (blocks < wblk) + dst histogram ============
__global__ void wtrans_hist_kernel(const float* __restrict__ p1w, const float* __restrict__ p2w,
                                   const float* __restrict__ k1w, const float* __restrict__ k2w,
                                   unsigned short* __restrict__ p1wt,
                                   unsigned short* __restrict__ p2wt,
                                   unsigned short* __restrict__ k1wt,
                                   unsigned short* __restrict__ k2wt,
                                   const int* __restrict__ ei0, const int* __restrict__ ei1,
                                   int E, int* __restrict__ deg, int N, int wblk) {
  if ((int)blockIdx.x < wblk) {
    int i = blockIdx.x * 256 + threadIdx.x;
    if (i < 32768) {                      // p1: [128,256]
      int k = i >> 8, f = i & 255;
      p1wt[f * 128 + k] = f2bf(p1w[i]);
    } else if (i < 65536) {               // p2: [256,128]
      int j = i - 32768; int k = j >> 7, f = j & 127;
      p2wt[f * 256 + k] = f2bf(p2w[j]);
    } else if (i < 131072) {              // k1: [256,256]
      int j = i - 65536; int k = j >> 8, f = j & 255;
      k1wt[f * 256 + k] = f2bf(k1w[j]);
    } else if (i < 147456) {              // k2: [128,128]
      int j = i - 131072; int k = j >> 7, f = j & 127;
      k2wt[f * 128 + k] = f2bf(k2w[j]);
    }
  } else {
    int i = (blockIdx.x - wblk) * 256 + threadIdx.x;
    if (i < 2 * E) {
      int r = i >= E;
      int e = i - (r ? E : 0);
      const int* ei = r ? ei1 : ei0;
      atomicAdd(&deg[r * N + ei[E + e]], 1);
    }
  }
}

__global__ void scan_local2_kernel(const int* __restrict__ deg, int* __restrict__ incl,
                                   int* __restrict__ bsum, int n, int nb) {
  __shared__ int tile[256];
  int r = blockIdx.x / nb;
  int b = blockIdx.x - r * nb;
  int i = b * 256 + threadIdx.x;
  int v = (i < n) ? deg[r * n + i] : 0;
  tile[threadIdx.x] = v;
  __syncthreads();
  for (int off = 1; off < 256; off <<= 1) {
    int t = (threadIdx.x >= (unsigned)off) ? tile[threadIdx.x - off] : 0;
    __syncthreads();
    tile[threadIdx.x] += t;
    __syncthreads();
  }
  if (i < n) incl[r * n + i] = tile[threadIdx.x];
  if (threadIdx.x == 255) bsum[blockIdx.x] = tile[255];
}

__global__ void scan_bsum2_kernel(int* __restrict__ bsum, int nb) {
  __shared__ int tile[256];
  int r = blockIdx.x;
  int v = (threadIdx.x < (unsigned)nb) ? bsum[r * nb + threadIdx.x] : 0;
  tile[threadIdx.x] = v;
  __syncthreads();
  for (int off = 1; off < 256; off <<= 1) {
    int t = (threadIdx.x >= (unsigned)off) ? tile[threadIdx.x - off] : 0;
    __syncthreads();
    tile[threadIdx.x] += t;
    __syncthreads();
  }
  if (threadIdx.x < (unsigned)nb) bsum[r * nb + threadIdx.x] = tile[threadIdx.x] - v;
}

__global__ void scan_fix2_kernel(const int* __restrict__ incl, const int* __restrict__ deg,
                                 const int* __restrict__ bsum, int* __restrict__ rp0,
                                 int* __restrict__ rp1, int n, int nb, int E) {
  int r = blockIdx.x / nb;
  int b = blockIdx.x - r * nb;
  int i = b * 256 + threadIdx.x;
  int* rp = r ? rp1 : rp0;
  if (i < n) rp[i] = incl[r * n + i] - deg[r * n + i] + bsum[blockIdx.x];
  if (i == 0) rp[n] = E;
}

__global__ void scatter2_kernel(const int* __restrict__ ei0, const int* __restrict__ ei1,
                                int E, const int* __restrict__ rp0, const int* __restrict__ rp1,
                                int* __restrict__ cur, int* __restrict__ cs0,
                                int* __restrict__ cs1, int N) {
  int i = blockIdx.x * blockDim.x + threadIdx.x;
  int tot = 2 * E;
  for (; i < tot; i += gridDim.x * blockDim.x) {
    int r = i >= E;
    int e = i - (r ? E : 0);
    const int* ei = r ? ei1 : ei0;
    const int* rp = r ? rp1 : rp0;
    int* cs = r ? cs1 : cs0;
    int dst = ei[E + e];
    int pos = rp[dst] + atomicAdd(&cur[r * N + dst], 1);
    cs[pos] = ei[e];  // src node id
  }
}

// =============== MFMA GEMM, direct-load (no LDS, no barriers) ===============
// A-fragment load per lane: row = m0+wrow+rt*16+l15, cols k0+l4*8.. — lanes
// (l15, l4=0..3) cover A[row][k0..k0+31] = contiguous 64B line; 16 rows/wave.
// MODE: 0 = A bf16; 1 = A fp32 (convert in-reg); 2 = A = bf16(a0*S0+a1*S1)
template <int K, int MODE>
__device__ __forceinline__ bf16x8 load_afrag(const unsigned short* __restrict__ A,
                                             const float* __restrict__ Af,
                                             const unsigned short* __restrict__ S0,
                                             const unsigned short* __restrict__ S1,
                                             float ca0, float ca1,
                                             int row, int koff, int M) {
  union { uint4 u; bf16x8 b; } cv;
  cv.u = (uint4){0u, 0u, 0u, 0u};
  if (row < M) {
    if constexpr (MODE == 0) {
      cv.u = *(const uint4*)&A[(size_t)row * K + koff];
    } else if constexpr (MODE == 1) {
      float4 f0 = *(const float4*)&Af[(size_t)row * K + koff];
      float4 f1 = *(const float4*)&Af[(size_t)row * K + koff + 4];
      cv.u.x = (unsigned)f2bf(f0.x) | ((unsigned)f2bf(f0.y) << 16);
      cv.u.y = (unsigned)f2bf(f0.z) | ((unsigned)f2bf(f0.w) << 16);
      cv.u.z = (unsigned)f2bf(f1.x) | ((unsigned)f2bf(f1.y) << 16);
      cv.u.w = (unsigned)f2bf(f1.z) | ((unsigned)f2bf(f1.w) << 16);
    } else {
      uint4 u0 = *(const uint4*)&S0[(size_t)row * K + koff];
      uint4 u1 = *(const uint4*)&S1[(size_t)row * K + koff];
      cv.u.x = comb2(u0.x, u1.x, ca0, ca1);
      cv.u.y = comb2(u0.y, u1.y, ca0, ca1);
      cv.u.z = comb2(u0.z, u1.z, ca0, ca1);
      cv.u.w = comb2(u0.w, u1.w, ca0, ca1);
    }
  }
  return cv.b;
}

#define MFMA_GEMM_CORE_D(K, F, BX, MODE)                                              \
  constexpr int G = F / 64, S = 4 / G, RT = 4 / S;                                    \
  const int tid = threadIdx.x;                                                        \
  const int lane = tid & 63, wid = tid >> 6;                                          \
  const int cg = wid % G, rg = wid / G;                                               \
  const int l15 = lane & 15, l4 = lane >> 4;                                          \
  const int m0 = (BX)*64;                                                             \
  const int wrow = rg * RT * 16;                                                      \
  f32x4 acc[RT][4];                                                                   \
  _Pragma("unroll") for (int rt = 0; rt < RT; ++rt)                                   \
  _Pragma("unroll") for (int ct = 0; ct < 4; ++ct)                                    \
      acc[rt][ct] = (f32x4){0.f, 0.f, 0.f, 0.f};                                      \
  _Pragma("unroll 2") for (int k0 = 0; k0 < K; k0 += 32) {                            \
    bf16x8 bfr[4];                                                                    \
    _Pragma("unroll") for (int ct = 0; ct < 4; ++ct)                                  \
      bfr[ct] = *(const bf16x8*)&Wt[(size_t)(cg * 64 + ct * 16 + l15) * K + k0 + l4 * 8]; \
    bf16x8 afr[RT];                                                                   \
    _Pragma("unroll") for (int rt = 0; rt < RT; ++rt)                                 \
      afr[rt] = load_afrag<K, MODE>(A, Af, S0, S1, ca0, ca1,                          \
                                    m0 + wrow + rt * 16 + l15, k0 + l4 * 8, M);       \
    _Pragma("unroll") for (int rt = 0; rt < RT; ++rt)                                 \
    _Pragma("unroll") for (int ct = 0; ct < 4; ++ct)                                  \
        acc[rt][ct] = __builtin_amdgcn_mfma_f32_16x16x32_bf16(                        \
            afr[rt], bfr[ct], acc[rt][ct], 0, 0, 0);                                  \
  }

// ---- proj GEMM with fused bias store + s/d epilogue ----
template <int K, int F, int MODE, int DD>
__global__ __launch_bounds__(256) void mfma_gemm_proj(
    const float* __restrict__ Af,
    const unsigned short* __restrict__ S0, const unsigned short* __restrict__ S1,
    const float* __restrict__ attnp, const unsigned short* __restrict__ Wt,
    const float* __restrict__ bias, unsigned short* __restrict__ out,
    const float* __restrict__ as0v, const float* __restrict__ ad0v,
    const float* __restrict__ as1v, const float* __restrict__ ad1v,
    float* __restrict__ s0g, float* __restrict__ d0g,
    float* __restrict__ s1g, float* __restrict__ d1g, int M) {
  float ca0 = 0.f, ca1 = 0.f;
  if constexpr (MODE == 2) { ca0 = attnp[0]; ca1 = attnp[1]; }
  const unsigned short* A = nullptr;
  MFMA_GEMM_CORE_D(K, F, blockIdx.x, MODE)
  // ---- bf16 h store ----
#pragma unroll
  for (int ct = 0; ct < 4; ++ct) {
    int n = cg * 64 + ct * 16 + l15;
    float bv = bias[n];
#pragma unroll
    for (int rt = 0; rt < RT; ++rt)
#pragma unroll
      for (int r = 0; r < 4; ++r) {
        int m = m0 + wrow + rt * 16 + l4 * 4 + r;
        if (m < M) out[(size_t)m * F + n] = f2bf(acc[rt][ct][r] + bv);
      }
  }
  // ---- fused s/d epilogue: per-head column reductions ----
  constexpr int HPW = 64 / DD, CTH = DD / 16;
#pragma unroll
  for (int hw = 0; hw < HPW; ++hw) {
    int head = cg * HPW + hw;
    float a0v[CTH], a1v[CTH], a2v[CTH], a3v[CTH], bvv[CTH];
#pragma unroll
    for (int c = 0; c < CTH; ++c) {
      int col = cg * 64 + (hw * CTH + c) * 16 + l15;
      a0v[c] = as0v[col]; a1v[c] = ad0v[col];
      a2v[c] = as1v[col]; a3v[c] = ad1v[col];
      bvv[c] = bias[col];
    }
#pragma unroll
    for (int rt = 0; rt < RT; ++rt) {
#pragma unroll
      for (int r = 0; r < 4; ++r) {
        float v0 = 0.f, v1 = 0.f, v2 = 0.f, v3 = 0.f;
#pragma unroll
        for (int c = 0; c < CTH; ++c) {
          float hval = acc[rt][hw * CTH + c][r] + bvv[c];
          v0 += hval * a0v[c]; v1 += hval * a1v[c];
          v2 += hval * a2v[c]; v3 += hval * a3v[c];
        }
#pragma unroll
        for (int off = 8; off > 0; off >>= 1) {
          v0 += __shfl_xor(v0, off, 16);
          v1 += __shfl_xor(v1, off, 16);
          v2 += __shfl_xor(v2, off, 16);
          v3 += __shfl_xor(v3, off, 16);
        }
        if (l15 == 0) {
          int m = m0 + wrow + rt * 16 + l4 * 4 + r;
          if (m < M) {
            int idx = m * NHEAD + head;
            s0g[idx] = v0; d0g[idx] = v1;
            s1g[idx] = v2; d1g[idx] = v3;
          }
        }
      }
    }
  }
}

// ---- semantic GEMM, both relations in one launch: slot-spread atomics ----
template <int K, int F>
__global__ __launch_bounds__(256) void mfma_gemm_tanh2(
    const unsigned short* __restrict__ A0, const unsigned short* __restrict__ A1,
    const unsigned short* __restrict__ Wt, const float* __restrict__ bias,
    float* __restrict__ wslots, int M, int half) {
  const unsigned short* A;
  float* ws = wslots + (blockIdx.x & (NSLOT - 1)) * SLOT_STRIDE;
  int bx = blockIdx.x;
  if (bx < half) { A = A0; }
  else { A = A1; ws += F; bx -= half; }
  const float* Af = nullptr;
  const unsigned short* S0 = nullptr; const unsigned short* S1 = nullptr;
  float ca0 = 0.f, ca1 = 0.f;
  MFMA_GEMM_CORE_D(K, F, bx, 0)
#pragma unroll
  for (int ct = 0; ct < 4; ++ct) {
    int n = cg * 64 + ct * 16 + l15;
    float bv = bias[n];
    float cs = 0.f;
#pragma unroll
    for (int rt = 0; rt < RT; ++rt)
#pragma unroll
      for (int r = 0; r < 4; ++r) {
        int m = m0 + wrow + rt * 16 + l4 * 4 + r;
        if (m < M) cs += fast_tanh(acc[rt][ct][r] + bv);
      }
    cs += __shfl_xor(cs, 16, 64);
    cs += __shfl_xor(cs, 32, 64);
    if (l4 == 0) atomicAdd(&ws[n], cs);
  }
}

// ---- fused per-dst softmax + weighted gather + relu; wave/node, 4-edge unroll ----
__device__ __forceinline__ void acc4(uint2 hv, float v, float* acc) {
  acc[0] += v * bf2f((unsigned short)(hv.x & 0xffff));
  acc[1] += v * bf2f((unsigned short)(hv.x >> 16));
  acc[2] += v * bf2f((unsigned short)(hv.y & 0xffff));
  acc[3] += v * bf2f((unsigned short)(hv.y >> 16));
}
__device__ __forceinline__ void acc2(unsigned int hv, float v, float* acc) {
  acc[0] += v * bf2f((unsigned short)(hv & 0xffff));
  acc[1] += v * bf2f((unsigned short)(hv >> 16));
}
__device__ __forceinline__ float ecoef(float sv, float dv) {
  float a = sv + dv;
  a = (a >= 0.f) ? a : 0.2f * a;
  return __expf(a);  // segment_max skipped: cancels in softmax, alpha is O(1)
}

template <int F, int D>
__global__ void message2_kernel(const unsigned short* __restrict__ h,
                                const int* __restrict__ cs0, const int* __restrict__ rp0,
                                const float* __restrict__ s0, const float* __restrict__ d0,
                                unsigned short* __restrict__ o0,
                                const int* __restrict__ cs1, const int* __restrict__ rp1,
                                const float* __restrict__ s1, const float* __restrict__ d1,
                                unsigned short* __restrict__ o1,
                                float* __restrict__ wslots,  // blocks 0..63 zero slot b
                                int N, int half) {
  constexpr int VEC = F / 64;
  if (blockIdx.x < NSLOT) {
    float* ws = wslots + blockIdx.x * SLOT_STRIDE;
    for (int i = threadIdx.x; i < 2 * F; i += 256) ws[i] = 0.f;
  }
  int b = blockIdx.x;
  const int* colsrc; const int* rp; const float* s; const float* d;
  unsigned short* out;
  if (b < half) { colsrc = cs0; rp = rp0; s = s0; d = d0; out = o0; }
  else { b -= half; colsrc = cs1; rp = rp1; s = s1; d = d1; out = o1; }
  int w = threadIdx.x >> 6;
  int lane = threadIdx.x & 63;
  int nn = b * 4 + w;
  if (nn >= N) return;
  int f0 = lane * VEC;
  int hh = f0 / D;
  float dv = d[nn * NHEAD + hh];
  int lo = rp[nn], hi = rp[nn + 1];
  float acc[VEC];
#pragma unroll
  for (int v = 0; v < VEC; ++v) acc[v] = 0.f;
  float den = 0.f;
  int j = lo;
  for (; j + 4 <= hi; j += 4) {
    int c0 = colsrc[j], c1 = colsrc[j + 1], c2 = colsrc[j + 2], c3 = colsrc[j + 3];
    float e0 = s[c0 * NHEAD + hh], e1 = s[c1 * NHEAD + hh];
    float e2 = s[c2 * NHEAD + hh], e3 = s[c3 * NHEAD + hh];
    if constexpr (VEC == 4) {
      uint2 h0 = *(const uint2*)&h[(size_t)c0 * F + f0];
      uint2 h1 = *(const uint2*)&h[(size_t)c1 * F + f0];
      uint2 h2 = *(const uint2*)&h[(size_t)c2 * F + f0];
      uint2 h3 = *(const uint2*)&h[(size_t)c3 * F + f0];
      float v0 = ecoef(e0, dv), v1 = ecoef(e1, dv);
      float v2 = ecoef(e2, dv), v3 = ecoef(e3, dv);
      den += v0 + v1 + v2 + v3;
      acc4(h0, v0, acc); acc4(h1, v1, acc);
      acc4(h2, v2, acc); acc4(h3, v3, acc);
    } else {
      unsigned int h0 = *(const unsigned int*)&h[(size_t)c0 * F + f0];
      unsigned int h1 = *(const unsigned int*)&h[(size_t)c1 * F + f0];
      unsigned int h2 = *(const unsigned int*)&h[(size_t)c2 * F + f0];
      unsigned int h3 = *(const unsigned int*)&h[(size_t)c3 * F + f0];
      float v0 = ecoef(e0, dv), v1 = ecoef(e1, dv);
      float v2 = ecoef(e2, dv), v3 = ecoef(e3, dv);
      den += v0 + v1 + v2 + v3;
      acc2(h0, v0, acc); acc2(h1, v1, acc);
      acc2(h2, v2, acc); acc2(h3, v3, acc);
    }
  }
  for (; j < hi; ++j) {
    int c = colsrc[j];
    float v = ecoef(s[c * NHEAD + hh], dv);
    den += v;
    if constexpr (VEC == 4) acc4(*(const uint2*)&h[(size_t)c * F + f0], v, acc);
    else acc2(*(const unsigned int*)&h[(size_t)c * F + f0], v, acc);
  }
  float inv = 1.f / (den + 1e-16f);
  if constexpr (VEC == 4) {
    uint2 o;
    o.x = (unsigned)f2bf(fmaxf(acc[0] * inv, 0.f)) |
          ((unsigned)f2bf(fmaxf(acc[1] * inv, 0.f)) << 16);
    o.y = (unsigned)f2bf(fmaxf(acc[2] * inv, 0.f)) |
          ((unsigned)f2bf(fmaxf(acc[3] * inv, 0.f)) << 16);
    *(uint2*)&out[(size_t)nn * F + f0] = o;
  } else {
    unsigned int o = (unsigned)f2bf(fmaxf(acc[0] * inv, 0.f)) |
                     ((unsigned)f2bf(fmaxf(acc[1] * inv, 0.f)) << 16);
    *(unsigned int*)&out[(size_t)nn * F + f0] = o;
  }
}

// ------- attn = softmax_r( mean_w_r . q ), reducing over NSLOT slots; opt zero psum -------
template <int F, bool ZP>
__global__ void attn_kernel(const float* __restrict__ wslots, const float* __restrict__ q,
                            float* __restrict__ attn, float inv_n,
                            float* __restrict__ psum, int pn) {
  __shared__ float red[2][F / 64];
  int f = threadIdx.x;
  if constexpr (ZP) {
    for (int i = f; i < pn; i += F) psum[i] = 0.f;
  }
  float w0 = 0.f, w1 = 0.f;
#pragma unroll 8
  for (int s = 0; s < NSLOT; ++s) {
    w0 += wslots[s * SLOT_STRIDE + f];
    w1 += wslots[s * SLOT_STRIDE + F + f];
  }
  float qv = q[f];
  float v0 = w0 * inv_n * qv;
  float v1 = w1 * inv_n * qv;
#pragma unroll
  for (int off = 32; off > 0; off >>= 1) {
    v0 += __shfl_down(v0, off, 64);
    v1 += __shfl_down(v1, off, 64);
  }
  int w = f / 64;
  if ((f & 63) == 0) { red[0][w] = v0; red[1][w] = v1; }
  __syncthreads();
  if (f == 0) {
    float d0 = 0.f, d1 = 0.f;
#pragma unroll
    for (int i = 0; i < F / 64; ++i) { d0 += red[0][i]; d1 += red[1][i]; }
    float m = fmaxf(d0, d1);
    float e0 = expf(d0 - m), e1 = expf(d1 - m);
    float inv = 1.f / (e0 + e1);
    attn[0] = e0 * inv;
    attn[1] = e1 * inv;
  }
}

// ------- pool with layer-2 combine fused (PCH=16 -> 3125 blocks, 1 wave each) -------
__global__ void pool_fused_kernel(const unsigned short* __restrict__ st0,
                                  const unsigned short* __restrict__ st1,
                                  const float* __restrict__ attn,
                                  const int* __restrict__ batch,
                                  float* __restrict__ psum, int n) {
  int c0 = blockIdx.x * PCH;
  if (c0 >= n) return;
  int lane = threadIdx.x;  // 64; 2 features each
  float a0 = attn[0], a1 = attn[1];
  int end = min(c0 + PCH, n);
  int g_cur = batch[c0];
  float acc0 = 0.f, acc1 = 0.f;
  for (int nn = c0; nn < end; ++nn) {
    int g = batch[nn];
    if (g != g_cur) {
      atomicAdd(&psum[g_cur * 128 + lane * 2], acc0);
      atomicAdd(&psum[g_cur * 128 + lane * 2 + 1], acc1);
      acc0 = acc1 = 0.f;
      g_cur = g;
    }
    unsigned int u0 = *(const unsigned int*)&st0[(size_t)nn * 128 + lane * 2];
    unsigned int u1 = *(const unsigned int*)&st1[(size_t)nn * 128 + lane * 2];
    acc0 += bf2f(f2bf(a0 * bf2f((unsigned short)(u0 & 0xffff)) +
                      a1 * bf2f((unsigned short)(u1 & 0xffff))));
    acc1 += bf2f(f2bf(a0 * bf2f((unsigned short)(u0 >> 16)) +
                      a1 * bf2f((unsigned short)(u1 >> 16))));
  }
  atomicAdd(&psum[g_cur * 128 + lane * 2], acc0);
  atomicAdd(&psum[g_cur * 128 + lane * 2 + 1], acc1);
}

__device__ __forceinline__ int lower_bound_i(const int* a, int n, int key) {
  int lo = 0, hi = n;
  while (lo < hi) {
    int mid = (lo + hi) >> 1;
    if (a[mid] < key) lo = mid + 1; else hi = mid;
  }
  return lo;
}

// ------- fused pool-final + MLP head: G blocks x 128 threads -------
__global__ void poolhead_kernel(const float* __restrict__ psum, const int* __restrict__ batch,
                                int n, const float* __restrict__ d1w,
                                const float* __restrict__ d1b, const float* __restrict__ gamma,
                                const float* __restrict__ beta, const float* __restrict__ mean,
                                const float* __restrict__ var, const float* __restrict__ d2w,
                                const float* __restrict__ d2b, float* __restrict__ out) {
  __shared__ float pool_sh[128];
  int g = blockIdx.x;
  int f = threadIdx.x;  // 128
  int lo = lower_bound_i(batch, n, g);
  int hi = lower_bound_i(batch, n, g + 1);
  float cnt = fmaxf((float)(hi - lo), 1.f);
  pool_sh[f] = psum[g * 128 + f] / cnt;
  __syncthreads();
  if (f < 64) {
    float acc = d1b[f];
#pragma unroll 8
    for (int k = 0; k < 128; ++k) acc += pool_sh[k] * d1w[k * 64 + f];
    float z = (acc - mean[f]) / sqrtf(var[f] + 1e-5f) * gamma[f] + beta[f];
    z = (z >= 0.f) ? z : 0.1f * z;
    float t = z * d2w[f];
#pragma unroll
    for (int off = 32; off > 0; off >>= 1) t += __shfl_down(t, off, 64);
    if (f == 0) out[g] = t + d2b[0];
  }
}

// =====================================================================
extern "C" void kernel_launch(void* const* d_in, const int* in_sizes, int n_in,
                              void* d_out, int out_size, void* d_ws, size_t ws_size,
                              hipStream_t stream) {
  const float* x      = (const float*)d_in[0];
  const int* ei0      = (const int*)d_in[1];
  const int* ei1      = (const int*)d_in[2];
  const int* batch    = (const int*)d_in[3];
  const float* p1w    = (const float*)d_in[4];
  const float* p1b    = (const float*)d_in[5];
  const float* as1r0  = (const float*)d_in[6];
  const float* ad1r0  = (const float*)d_in[7];
  const float* as1r1  = (const float*)d_in[8];
  const float* ad1r1  = (const float*)d_in[9];
  const float* kl1w   = (const float*)d_in[10];
  const float* kl1b   = (const float*)d_in[11];
  const float* q1     = (const float*)d_in[12];
  const float* p2w    = (const float*)d_in[13];
  const float* p2b    = (const float*)d_in[14];
  const float* as2r0  = (const float*)d_in[15];
  const float* ad2r0  = (const float*)d_in[16];
  const float* as2r1  = (const float*)d_in[17];
  const float* ad2r1  = (const float*)d_in[18];
  const float* kl2w   = (const float*)d_in[19];
  const float* kl2b   = (const float*)d_in[20];
  const float* q2     = (const float*)d_in[21];
  const float* d1w    = (const float*)d_in[22];
  const float* d1b    = (const float*)d_in[23];
  const float* bng    = (const float*)d_in[24];
  const float* bnb    = (const float*)d_in[25];
  const float* bnm    = (const float*)d_in[26];
  const float* bnv    = (const float*)d_in[27];
  const float* d2w    = (const float*)d_in[28];
  const float* d2b    = (const float*)d_in[29];
  float* out = (float*)d_out;

  const int N = in_sizes[3];       // 50000
  const int E = in_sizes[1] / 2;   // 400000
  const int G = 64;

  char* p = (char*)d_ws;
  auto alloc = [&](size_t bytes) -> void* {
    void* r = (void*)p;
    p += (bytes + 255) & ~(size_t)255;
    return r;
  };
  int* rp0    = (int*)alloc((N + 1) * sizeof(int));
  int* rp1    = (int*)alloc((N + 1) * sizeof(int));
  int* cs0    = (int*)alloc(E * sizeof(int));        // src per CSR slot
  int* cs1    = (int*)alloc(E * sizeof(int));
  int* deg    = (int*)alloc(2 * (size_t)N * sizeof(int));   // deg+cur: one memset
  int* cur    = (int*)alloc(2 * (size_t)N * sizeof(int));
  int* incl   = (int*)alloc(2 * (size_t)N * sizeof(int));
  int* bsum   = (int*)alloc(512 * sizeof(int));
  unsigned short* h_bf  = (unsigned short*)alloc((size_t)N * 256 * 2);
  unsigned short* st0   = (unsigned short*)alloc((size_t)N * 256 * 2);
  unsigned short* st1   = (unsigned short*)alloc((size_t)N * 256 * 2);
  unsigned short* h2_bf = (unsigned short*)alloc((size_t)N * 128 * 2);
  unsigned short* p1wt  = (unsigned short*)alloc(128 * 256 * 2);
  unsigned short* p2wt  = (unsigned short*)alloc(256 * 128 * 2);
  unsigned short* k1wt  = (unsigned short*)alloc(256 * 256 * 2);
  unsigned short* k2wt  = (unsigned short*)alloc(128 * 128 * 2);
  float* s0     = (float*)alloc((size_t)N * NHEAD * sizeof(float));
  float* d0     = (float*)alloc((size_t)N * NHEAD * sizeof(float));
  float* s1     = (float*)alloc((size_t)N * NHEAD * sizeof(float));
  float* d1     = (float*)alloc((size_t)N * NHEAD * sizeof(float));
  float* wslots = (float*)alloc((size_t)NSLOT * SLOT_STRIDE * sizeof(float));
  float* attn1  = (float*)alloc(2 * sizeof(float));
  float* attn2  = (float*)alloc(2 * sizeof(float));
  float* psum   = (float*)alloc((size_t)G * 128 * sizeof(float));

  // ---- 1: zero deg+cur (contiguous allocs -> single memset) ----
  size_t zlen = (size_t)((char*)cur - (char*)deg) + 2 * (size_t)N * sizeof(int);
  hipMemsetAsync(deg, 0, zlen, stream);

  // ---- 2: weight transpose+cast fused with dst histogram ----
  int wblk = 576;  // 147456 / 256
  int e2blk = (2 * E + 255) / 256;
  wtrans_hist_kernel<<<wblk + e2blk, 256, 0, stream>>>(
      p1w, p2w, kl1w, kl2w, p1wt, p2wt, k1wt, k2wt, ei0, ei1, E, deg, N, wblk);

  // ---- 3-6: scan + scatter ----
  int nb = (N + 255) / 256;
  scan_local2_kernel<<<2 * nb, 256, 0, stream>>>(deg, incl, bsum, N, nb);
  scan_bsum2_kernel<<<2, 256, 0, stream>>>(bsum, nb);
  scan_fix2_kernel<<<2 * nb, 256, 0, stream>>>(incl, deg, bsum, rp0, rp1, N, nb, E);
  scatter2_kernel<<<e2blk, 256, 0, stream>>>(ei0, ei1, E, rp0, rp1, cur, cs0, cs1, N);

  int gblk = (N + 63) / 64;
  int nblk4 = (N + 3) / 4;

  // ================= layer 1: 128 -> 256, D=64 =================
  mfma_gemm_proj<128, 256, 1, 64><<<gblk, 256, 0, stream>>>(
      x, nullptr, nullptr, nullptr, p1wt, p1b, h_bf,
      as1r0, ad1r0, as1r1, ad1r1, s0, d0, s1, d1, N);
  message2_kernel<256, 64><<<2 * nblk4, 256, 0, stream>>>(
      h_bf, cs0, rp0, s0, d0, st0, cs1, rp1, s1, d1, st1, wslots, N, nblk4);
  mfma_gemm_tanh2<256, 256><<<2 * gblk, 256, 0, stream>>>(
      st0, st1, k1wt, kl1b, wslots, N, gblk);
  attn_kernel<256, false><<<1, 256, 0, stream>>>(wslots, q1, attn1, 1.0f / (float)N,
                                                 nullptr, 0);

  // ================= layer 2: 256 -> 128, D=32 =================
  mfma_gemm_proj<256, 128, 2, 32><<<gblk, 256, 0, stream>>>(
      nullptr, st0, st1, attn1, p2wt, p2b, h2_bf,
      as2r0, ad2r0, as2r1, ad2r1, s0, d0, s1, d1, N);
  message2_kernel<128, 32><<<2 * nblk4, 256, 0, stream>>>(
      h2_bf, cs0, rp0, s0, d0, st0, cs1, rp1, s1, d1, st1, wslots, N, nblk4);
  mfma_gemm_tanh2<128, 128><<<2 * gblk, 256, 0, stream>>>(
      st0, st1, k2wt, kl2b, wslots, N, gblk);
  attn_kernel<128, true><<<1, 128, 0, stream>>>(wslots, q2, attn2, 1.0f / (float)N,
                                                psum, G * 128);

  // ---- pool (combine fused) + fused final/head ----
  int pblk = (N + PCH - 1) / PCH;
  pool_fused_kernel<<<pblk, 64, 0, stream>>>(st0, st1, attn2, batch, psum, N);
  poolhead_kernel<<<G, 128, 0, stream>>>(psum, batch, N, d1w, d1b, bng, bnb, bnm, bnv,
                                         d2w, d2b, out);
}

// Round 11
// 360.825 us; speedup vs baseline: 1.1378x; 1.1378x over previous
//
#include <hip/hip_runtime.h>
#include <math.h>

#define NHEAD 4
#define PCH 16
#define NSLOT 64
#define SLOT_STRIDE 512  // floats per slot (>= 2F for both layers)

typedef __bf16 bf16x8 __attribute__((ext_vector_type(8)));
typedef float f32x4 __attribute__((ext_vector_type(4)));

__device__ __forceinline__ unsigned short f2bf(float f) {
  unsigned int u = __float_as_uint(f);
  u += 0x7FFF + ((u >> 16) & 1);  // round-to-nearest-even
  return (unsigned short)(u >> 16);
}
__device__ __forceinline__ float bf2f(unsigned short s) {
  return __uint_as_float(((unsigned int)s) << 16);
}
__device__ __forceinline__ unsigned int comb2(unsigned int p, unsigned int q,
                                              float a0, float a1) {
  float lo = a0 * bf2f((unsigned short)p) + a1 * bf2f((unsigned short)q);
  float hi = a0 * bf2f((unsigned short)(p >> 16)) + a1 * bf2f((unsigned short)(q >> 16));
  return (unsigned)f2bf(lo) | ((unsigned)f2bf(hi) << 16);
}
__device__ __forceinline__ float fast_tanh(float x) {
  x = fminf(fmaxf(x, -15.f), 15.f);
  float e = __expf(2.f * x);
  return (e - 1.f) / (e + 1.f);
}

// ---- pack W[K][F] into MFMA-fragment order ----
// out[((ft*(K/32)+kt)*64 + lane)*8 + j] = bf16( W[kt*32 + (lane>>4)*8 + j][ft*16 + (lane&15)] )
// => a wave's B-fragment load for (col-tile ft, k-tile kt) is ONE contiguous 1KB read.
__device__ __forceinline__ void pack_one(const float* __restrict__ W,
                                         unsigned short* __restrict__ out,
                                         int K, int F, int j) {
  int nkt = K >> 5;
  int chunk = nkt << 9;  // nkt*512
  int ft = j / chunk;
  int rem = j - ft * chunk;
  int kt = rem >> 9;
  int rem2 = rem & 511;
  int lane = rem2 >> 3;
  int jj = rem2 & 7;
  int k = (kt << 5) + ((lane >> 4) << 3) + jj;
  int f = (ft << 4) + (lane & 15);
  out[j] = f2bf(W[(size_t)k * F + f]);
}

// ============ combined: weight fragment-pack (blocks < wblk) + dst histogram ============
__global__ void wtrans_hist_kernel(const float* __restrict__ p1w, const float* __restrict__ p2w,
                                   const float* __restrict__ k1w, const float* __restrict__ k2w,
                                   unsigned short* __restrict__ p1wt,
                                   unsigned short* __restrict__ p2wt,
                                   unsigned short* __restrict__ k1wt,
                                   unsigned short* __restrict__ k2wt,
                                   const int* __restrict__ ei0, const int* __restrict__ ei1,
                                   int E, int* __restrict__ deg, int N, int wblk) {
  if ((int)blockIdx.x < wblk) {
    int i = blockIdx.x * 256 + threadIdx.x;
    if (i < 32768) {                      // p1: [128,256]
      pack_one(p1w, p1wt, 128, 256, i);
    } else if (i < 65536) {               // p2: [256,128]
      pack_one(p2w, p2wt, 256, 128, i - 32768);
    } else if (i < 131072) {              // k1: [256,256]
      pack_one(k1w, k1wt, 256, 256, i - 65536);
    } else if (i < 147456) {              // k2: [128,128]
      pack_one(k2w, k2wt, 128, 128, i - 131072);
    }
  } else {
    int i = (blockIdx.x - wblk) * 256 + threadIdx.x;
    if (i < 2 * E) {
      int r = i >= E;
      int e = i - (r ? E : 0);
      const int* ei = r ? ei1 : ei0;
      atomicAdd(&deg[r * N + ei[E + e]], 1);
    }
  }
}

__global__ void scan_local2_kernel(const int* __restrict__ deg, int* __restrict__ incl,
                                   int* __restrict__ bsum, int n, int nb) {
  __shared__ int tile[256];
  int r = blockIdx.x / nb;
  int b = blockIdx.x - r * nb;
  int i = b * 256 + threadIdx.x;
  int v = (i < n) ? deg[r * n + i] : 0;
  tile[threadIdx.x] = v;
  __syncthreads();
  for (int off = 1; off < 256; off <<= 1) {
    int t = (threadIdx.x >= (unsigned)off) ? tile[threadIdx.x - off] : 0;
    __syncthreads();
    tile[threadIdx.x] += t;
    __syncthreads();
  }
  if (i < n) incl[r * n + i] = tile[threadIdx.x];
  if (threadIdx.x == 255) bsum[blockIdx.x] = tile[255];
}

__global__ void scan_bsum2_kernel(int* __restrict__ bsum, int nb) {
  __shared__ int tile[256];
  int r = blockIdx.x;
  int v = (threadIdx.x < (unsigned)nb) ? bsum[r * nb + threadIdx.x] : 0;
  tile[threadIdx.x] = v;
  __syncthreads();
  for (int off = 1; off < 256; off <<= 1) {
    int t = (threadIdx.x >= (unsigned)off) ? tile[threadIdx.x - off] : 0;
    __syncthreads();
    tile[threadIdx.x] += t;
    __syncthreads();
  }
  if (threadIdx.x < (unsigned)nb) bsum[r * nb + threadIdx.x] = tile[threadIdx.x] - v;
}

__global__ void scan_fix2_kernel(const int* __restrict__ incl, const int* __restrict__ deg,
                                 const int* __restrict__ bsum, int* __restrict__ rp0,
                                 int* __restrict__ rp1, int n, int nb, int E) {
  int r = blockIdx.x / nb;
  int b = blockIdx.x - r * nb;
  int i = b * 256 + threadIdx.x;
  int* rp = r ? rp1 : rp0;
  if (i < n) rp[i] = incl[r * n + i] - deg[r * n + i] + bsum[blockIdx.x];
  if (i == 0) rp[n] = E;
}

__global__ void scatter2_kernel(const int* __restrict__ ei0, const int* __restrict__ ei1,
                                int E, const int* __restrict__ rp0, const int* __restrict__ rp1,
                                int* __restrict__ cur, int* __restrict__ cs0,
                                int* __restrict__ cs1, int N) {
  int i = blockIdx.x * blockDim.x + threadIdx.x;
  int tot = 2 * E;
  for (; i < tot; i += gridDim.x * blockDim.x) {
    int r = i >= E;
    int e = i - (r ? E : 0);
    const int* ei = r ? ei1 : ei0;
    const int* rp = r ? rp1 : rp0;
    int* cs = r ? cs1 : cs0;
    int dst = ei[E + e];
    int pos = rp[dst] + atomicAdd(&cur[r * N + dst], 1);
    cs[pos] = ei[e];  // src node id
  }
}

// =============== MFMA GEMM core: 64 rows x F cols/block, 256 thr, 16x16x32 bf16 ===============
// A staged coalesced through LDS; B loaded from fragment-packed Wtp (1KB contiguous per frag).
#define MFMA_GEMM_CORE(K, F, BX)                                                      \
  constexpr int G = F / 64, S = 4 / G, RT = 4 / S;                                    \
  constexpr int NKT = K / 32;                                                         \
  __shared__ unsigned short As[64][40]; /* pad 40: bank spread, rows 16B-aligned */   \
  const int tid = threadIdx.x;                                                        \
  const int lane = tid & 63, wid = tid >> 6;                                          \
  const int cg = wid % G, rg = wid / G;                                               \
  const int l15 = lane & 15, l4 = lane >> 4;                                          \
  const int m0 = (BX)*64;                                                             \
  const int wrow = rg * RT * 16;                                                      \
  f32x4 acc[RT][4];                                                                   \
  _Pragma("unroll") for (int rt = 0; rt < RT; ++rt)                                   \
  _Pragma("unroll") for (int ct = 0; ct < 4; ++ct)                                    \
      acc[rt][ct] = (f32x4){0.f, 0.f, 0.f, 0.f};                                      \
  const int arow = tid >> 2;                                                          \
  const int akk = (tid & 3) * 8;                                                      \
  for (int k0 = 0; k0 < K; k0 += 32) {                                                \
    const int kt = k0 >> 5;                                                           \
    uint4 av = {0u, 0u, 0u, 0u};                                                      \
    int row = m0 + arow;                                                              \
    if (row < M) { MFMA_LOAD_A }                                                      \
    __syncthreads();                                                                  \
    *(uint4*)&As[arow][akk] = av;                                                     \
    __syncthreads();                                                                  \
    bf16x8 bfr[4];                                                                    \
    _Pragma("unroll") for (int ct = 0; ct < 4; ++ct)                                  \
      bfr[ct] = *(const bf16x8*)&Wtp[((((cg * 4 + ct) * NKT + kt) * 64 + lane) << 3)];\
    _Pragma("unroll") for (int rt = 0; rt < RT; ++rt) {                               \
      bf16x8 afr = *(const bf16x8*)&As[wrow + rt * 16 + l15][l4 * 8];                 \
      _Pragma("unroll") for (int ct = 0; ct < 4; ++ct)                                \
        acc[rt][ct] = __builtin_amdgcn_mfma_f32_16x16x32_bf16(                        \
            afr, bfr[ct], acc[rt][ct], 0, 0, 0);                                      \
    }                                                                                 \
  }

// ---- proj GEMM with fused bias store + s/d epilogue ----
// MODE: 1 = A fp32 (convert in staging); 2 = A = bf16(a0*S0 + a1*S1)
template <int K, int F, int MODE, int DD>
__global__ __launch_bounds__(256) void mfma_gemm_proj(
    const float* __restrict__ Af,
    const unsigned short* __restrict__ S0, const unsigned short* __restrict__ S1,
    const float* __restrict__ attnp, const unsigned short* __restrict__ Wtp,
    const float* __restrict__ bias, unsigned short* __restrict__ out,
    const float* __restrict__ as0v, const float* __restrict__ ad0v,
    const float* __restrict__ as1v, const float* __restrict__ ad1v,
    float* __restrict__ s0g, float* __restrict__ d0g,
    float* __restrict__ s1g, float* __restrict__ d1g, int M) {
  float ca0 = 0.f, ca1 = 0.f;
  if constexpr (MODE == 2) { ca0 = attnp[0]; ca1 = attnp[1]; }
#define MFMA_LOAD_A                                                                   \
  if constexpr (MODE == 1) {                                                          \
    float4 f0 = *(const float4*)&Af[(size_t)row * K + k0 + akk];                      \
    float4 f1 = *(const float4*)&Af[(size_t)row * K + k0 + akk + 4];                  \
    av.x = (unsigned)f2bf(f0.x) | ((unsigned)f2bf(f0.y) << 16);                       \
    av.y = (unsigned)f2bf(f0.z) | ((unsigned)f2bf(f0.w) << 16);                       \
    av.z = (unsigned)f2bf(f1.x) | ((unsigned)f2bf(f1.y) << 16);                       \
    av.w = (unsigned)f2bf(f1.z) | ((unsigned)f2bf(f1.w) << 16);                       \
  } else {                                                                            \
    uint4 u0 = *(const uint4*)&S0[(size_t)row * K + k0 + akk];                        \
    uint4 u1 = *(const uint4*)&S1[(size_t)row * K + k0 + akk];                        \
    av.x = comb2(u0.x, u1.x, ca0, ca1);                                               \
    av.y = comb2(u0.y, u1.y, ca0, ca1);                                               \
    av.z = comb2(u0.z, u1.z, ca0, ca1);                                               \
    av.w = comb2(u0.w, u1.w, ca0, ca1);                                               \
  }
  MFMA_GEMM_CORE(K, F, blockIdx.x)
#undef MFMA_LOAD_A
  // ---- bf16 h store ----
#pragma unroll
  for (int ct = 0; ct < 4; ++ct) {
    int n = cg * 64 + ct * 16 + l15;
    float bv = bias[n];
#pragma unroll
    for (int rt = 0; rt < RT; ++rt)
#pragma unroll
      for (int r = 0; r < 4; ++r) {
        int m = m0 + wrow + rt * 16 + l4 * 4 + r;
        if (m < M) out[(size_t)m * F + n] = f2bf(acc[rt][ct][r] + bv);
      }
  }
  // ---- fused s/d epilogue: per-head column reductions ----
  constexpr int HPW = 64 / DD, CTH = DD / 16;
#pragma unroll
  for (int hw = 0; hw < HPW; ++hw) {
    int head = cg * HPW + hw;
    float a0v[CTH], a1v[CTH], a2v[CTH], a3v[CTH], bvv[CTH];
#pragma unroll
    for (int c = 0; c < CTH; ++c) {
      int col = cg * 64 + (hw * CTH + c) * 16 + l15;
      a0v[c] = as0v[col]; a1v[c] = ad0v[col];
      a2v[c] = as1v[col]; a3v[c] = ad1v[col];
      bvv[c] = bias[col];
    }
#pragma unroll
    for (int rt = 0; rt < RT; ++rt) {
#pragma unroll
      for (int r = 0; r < 4; ++r) {
        float v0 = 0.f, v1 = 0.f, v2 = 0.f, v3 = 0.f;
#pragma unroll
        for (int c = 0; c < CTH; ++c) {
          float hval = acc[rt][hw * CTH + c][r] + bvv[c];
          v0 += hval * a0v[c]; v1 += hval * a1v[c];
          v2 += hval * a2v[c]; v3 += hval * a3v[c];
        }
#pragma unroll
        for (int off = 8; off > 0; off >>= 1) {
          v0 += __shfl_xor(v0, off, 16);
          v1 += __shfl_xor(v1, off, 16);
          v2 += __shfl_xor(v2, off, 16);
          v3 += __shfl_xor(v3, off, 16);
        }
        if (l15 == 0) {
          int m = m0 + wrow + rt * 16 + l4 * 4 + r;
          if (m < M) {
            int idx = m * NHEAD + head;
            s0g[idx] = v0; d0g[idx] = v1;
            s1g[idx] = v2; d1g[idx] = v3;
          }
        }
      }
    }
  }
}

// ---- semantic GEMM, both relations in one launch: slot-spread atomics ----
template <int K, int F>
__global__ __launch_bounds__(256) void mfma_gemm_tanh2(
    const unsigned short* __restrict__ A0, const unsigned short* __restrict__ A1,
    const unsigned short* __restrict__ Wtp, const float* __restrict__ bias,
    float* __restrict__ wslots, int M, int half) {
  const unsigned short* A;
  float* ws = wslots + (blockIdx.x & (NSLOT - 1)) * SLOT_STRIDE;
  int bx = blockIdx.x;
  if (bx < half) { A = A0; }
  else { A = A1; ws += F; bx -= half; }
#define MFMA_LOAD_A av = *(const uint4*)&A[(size_t)row * K + k0 + akk];
  MFMA_GEMM_CORE(K, F, bx)
#undef MFMA_LOAD_A
#pragma unroll
  for (int ct = 0; ct < 4; ++ct) {
    int n = cg * 64 + ct * 16 + l15;
    float bv = bias[n];
    float cs = 0.f;
#pragma unroll
    for (int rt = 0; rt < RT; ++rt)
#pragma unroll
      for (int r = 0; r < 4; ++r) {
        int m = m0 + wrow + rt * 16 + l4 * 4 + r;
        if (m < M) cs += fast_tanh(acc[rt][ct][r] + bv);
      }
    cs += __shfl_xor(cs, 16, 64);
    cs += __shfl_xor(cs, 32, 64);
    if (l4 == 0) atomicAdd(&ws[n], cs);
  }
}

// ---- fused per-dst softmax + weighted gather + relu; wave/node, 4-edge unroll ----
__device__ __forceinline__ void acc4(uint2 hv, float v, float* acc) {
  acc[0] += v * bf2f((unsigned short)(hv.x & 0xffff));
  acc[1] += v * bf2f((unsigned short)(hv.x >> 16));
  acc[2] += v * bf2f((unsigned short)(hv.y & 0xffff));
  acc[3] += v * bf2f((unsigned short)(hv.y >> 16));
}
__device__ __forceinline__ void acc2(unsigned int hv, float v, float* acc) {
  acc[0] += v * bf2f((unsigned short)(hv & 0xffff));
  acc[1] += v * bf2f((unsigned short)(hv >> 16));
}
__device__ __forceinline__ float ecoef(float sv, float dv) {
  float a = sv + dv;
  a = (a >= 0.f) ? a : 0.2f * a;
  return __expf(a);  // segment_max skipped: cancels in softmax, alpha is O(1)
}

template <int F, int D>
__global__ void message2_kernel(const unsigned short* __restrict__ h,
                                const int* __restrict__ cs0, const int* __restrict__ rp0,
                                const float* __restrict__ s0, const float* __restrict__ d0,
                                unsigned short* __restrict__ o0,
                                const int* __restrict__ cs1, const int* __restrict__ rp1,
                                const float* __restrict__ s1, const float* __restrict__ d1,
                                unsigned short* __restrict__ o1,
                                float* __restrict__ wslots,  // blocks 0..63 zero slot b
                                int N, int half) {
  constexpr int VEC = F / 64;
  if (blockIdx.x < NSLOT) {
    float* ws = wslots + blockIdx.x * SLOT_STRIDE;
    for (int i = threadIdx.x; i < 2 * F; i += 256) ws[i] = 0.f;
  }
  int b = blockIdx.x;
  const int* colsrc; const int* rp; const float* s; const float* d;
  unsigned short* out;
  if (b < half) { colsrc = cs0; rp = rp0; s = s0; d = d0; out = o0; }
  else { b -= half; colsrc = cs1; rp = rp1; s = s1; d = d1; out = o1; }
  int w = threadIdx.x >> 6;
  int lane = threadIdx.x & 63;
  int nn = b * 4 + w;
  if (nn >= N) return;
  int f0 = lane * VEC;
  int hh = f0 / D;
  float dv = d[nn * NHEAD + hh];
  int lo = rp[nn], hi = rp[nn + 1];
  float acc[VEC];
#pragma unroll
  for (int v = 0; v < VEC; ++v) acc[v] = 0.f;
  float den = 0.f;
  int j = lo;
  for (; j + 4 <= hi; j += 4) {
    int c0 = colsrc[j], c1 = colsrc[j + 1], c2 = colsrc[j + 2], c3 = colsrc[j + 3];
    float e0 = s[c0 * NHEAD + hh], e1 = s[c1 * NHEAD + hh];
    float e2 = s[c2 * NHEAD + hh], e3 = s[c3 * NHEAD + hh];
    if constexpr (VEC == 4) {
      uint2 h0 = *(const uint2*)&h[(size_t)c0 * F + f0];
      uint2 h1 = *(const uint2*)&h[(size_t)c1 * F + f0];
      uint2 h2 = *(const uint2*)&h[(size_t)c2 * F + f0];
      uint2 h3 = *(const uint2*)&h[(size_t)c3 * F + f0];
      float v0 = ecoef(e0, dv), v1 = ecoef(e1, dv);
      float v2 = ecoef(e2, dv), v3 = ecoef(e3, dv);
      den += v0 + v1 + v2 + v3;
      acc4(h0, v0, acc); acc4(h1, v1, acc);
      acc4(h2, v2, acc); acc4(h3, v3, acc);
    } else {
      unsigned int h0 = *(const unsigned int*)&h[(size_t)c0 * F + f0];
      unsigned int h1 = *(const unsigned int*)&h[(size_t)c1 * F + f0];
      unsigned int h2 = *(const unsigned int*)&h[(size_t)c2 * F + f0];
      unsigned int h3 = *(const unsigned int*)&h[(size_t)c3 * F + f0];
      float v0 = ecoef(e0, dv), v1 = ecoef(e1, dv);
      float v2 = ecoef(e2, dv), v3 = ecoef(e3, dv);
      den += v0 + v1 + v2 + v3;
      acc2(h0, v0, acc); acc2(h1, v1, acc);
      acc2(h2, v2, acc); acc2(h3, v3, acc);
    }
  }
  for (; j < hi; ++j) {
    int c = colsrc[j];
    float v = ecoef(s[c * NHEAD + hh], dv);
    den += v;
    if constexpr (VEC == 4) acc4(*(const uint2*)&h[(size_t)c * F + f0], v, acc);
    else acc2(*(const unsigned int*)&h[(size_t)c * F + f0], v, acc);
  }
  float inv = 1.f / (den + 1e-16f);
  if constexpr (VEC == 4) {
    uint2 o;
    o.x = (unsigned)f2bf(fmaxf(acc[0] * inv, 0.f)) |
          ((unsigned)f2bf(fmaxf(acc[1] * inv, 0.f)) << 16);
    o.y = (unsigned)f2bf(fmaxf(acc[2] * inv, 0.f)) |
          ((unsigned)f2bf(fmaxf(acc[3] * inv, 0.f)) << 16);
    *(uint2*)&out[(size_t)nn * F + f0] = o;
  } else {
    unsigned int o = (unsigned)f2bf(fmaxf(acc[0] * inv, 0.f)) |
                     ((unsigned)f2bf(fmaxf(acc[1] * inv, 0.f)) << 16);
    *(unsigned int*)&out[(size_t)nn * F + f0] = o;
  }
}

// ------- attn = softmax_r( mean_w_r . q ), reducing over NSLOT slots; opt zero psum -------
template <int F, bool ZP>
__global__ void attn_kernel(const float* __restrict__ wslots, const float* __restrict__ q,
                            float* __restrict__ attn, float inv_n,
                            float* __restrict__ psum, int pn) {
  __shared__ float red[2][F / 64];
  int f = threadIdx.x;
  if constexpr (ZP) {
    for (int i = f; i < pn; i += F) psum[i] = 0.f;
  }
  float w0 = 0.f, w1 = 0.f;
#pragma unroll 8
  for (int s = 0; s < NSLOT; ++s) {
    w0 += wslots[s * SLOT_STRIDE + f];
    w1 += wslots[s * SLOT_STRIDE + F + f];
  }
  float qv = q[f];
  float v0 = w0 * inv_n * qv;
  float v1 = w1 * inv_n * qv;
#pragma unroll
  for (int off = 32; off > 0; off >>= 1) {
    v0 += __shfl_down(v0, off, 64);
    v1 += __shfl_down(v1, off, 64);
  }
  int w = f / 64;
  if ((f & 63) == 0) { red[0][w] = v0; red[1][w] = v1; }
  __syncthreads();
  if (f == 0) {
    float d0 = 0.f, d1 = 0.f;
#pragma unroll
    for (int i = 0; i < F / 64; ++i) { d0 += red[0][i]; d1 += red[1][i]; }
    float m = fmaxf(d0, d1);
    float e0 = expf(d0 - m), e1 = expf(d1 - m);
    float inv = 1.f / (e0 + e1);
    attn[0] = e0 * inv;
    attn[1] = e1 * inv;
  }
}

// ------- pool with layer-2 combine fused (PCH=16 -> 3125 blocks, 1 wave each) -------
__global__ void pool_fused_kernel(const unsigned short* __restrict__ st0,
                                  const unsigned short* __restrict__ st1,
                                  const float* __restrict__ attn,
                                  const int* __restrict__ batch,
                                  float* __restrict__ psum, int n) {
  int c0 = blockIdx.x * PCH;
  if (c0 >= n) return;
  int lane = threadIdx.x;  // 64; 2 features each
  float a0 = attn[0], a1 = attn[1];
  int end = min(c0 + PCH, n);
  int g_cur = batch[c0];
  float acc0 = 0.f, acc1 = 0.f;
  for (int nn = c0; nn < end; ++nn) {
    int g = batch[nn];
    if (g != g_cur) {
      atomicAdd(&psum[g_cur * 128 + lane * 2], acc0);
      atomicAdd(&psum[g_cur * 128 + lane * 2 + 1], acc1);
      acc0 = acc1 = 0.f;
      g_cur = g;
    }
    unsigned int u0 = *(const unsigned int*)&st0[(size_t)nn * 128 + lane * 2];
    unsigned int u1 = *(const unsigned int*)&st1[(size_t)nn * 128 + lane * 2];
    acc0 += bf2f(f2bf(a0 * bf2f((unsigned short)(u0 & 0xffff)) +
                      a1 * bf2f((unsigned short)(u1 & 0xffff))));
    acc1 += bf2f(f2bf(a0 * bf2f((unsigned short)(u0 >> 16)) +
                      a1 * bf2f((unsigned short)(u1 >> 16))));
  }
  atomicAdd(&psum[g_cur * 128 + lane * 2], acc0);
  atomicAdd(&psum[g_cur * 128 + lane * 2 + 1], acc1);
}

__device__ __forceinline__ int lower_bound_i(const int* a, int n, int key) {
  int lo = 0, hi = n;
  while (lo < hi) {
    int mid = (lo + hi) >> 1;
    if (a[mid] < key) lo = mid + 1; else hi = mid;
  }
  return lo;
}

// ------- fused pool-final + MLP head: G blocks x 128 threads -------
__global__ void poolhead_kernel(const float* __restrict__ psum, const int* __restrict__ batch,
                                int n, const float* __restrict__ d1w,
                                const float* __restrict__ d1b, const float* __restrict__ gamma,
                                const float* __restrict__ beta, const float* __restrict__ mean,
                                const float* __restrict__ var, const float* __restrict__ d2w,
                                const float* __restrict__ d2b, float* __restrict__ out) {
  __shared__ float pool_sh[128];
  int g = blockIdx.x;
  int f = threadIdx.x;  // 128
  int lo = lower_bound_i(batch, n, g);
  int hi = lower_bound_i(batch, n, g + 1);
  float cnt = fmaxf((float)(hi - lo), 1.f);
  pool_sh[f] = psum[g * 128 + f] / cnt;
  __syncthreads();
  if (f < 64) {
    float acc = d1b[f];
#pragma unroll 8
    for (int k = 0; k < 128; ++k) acc += pool_sh[k] * d1w[k * 64 + f];
    float z = (acc - mean[f]) / sqrtf(var[f] + 1e-5f) * gamma[f] + beta[f];
    z = (z >= 0.f) ? z : 0.1f * z;
    float t = z * d2w[f];
#pragma unroll
    for (int off = 32; off > 0; off >>= 1) t += __shfl_down(t, off, 64);
    if (f == 0) out[g] = t + d2b[0];
  }
}

// =====================================================================
extern "C" void kernel_launch(void* const* d_in, const int* in_sizes, int n_in,
                              void* d_out, int out_size, void* d_ws, size_t ws_size,
                              hipStream_t stream) {
  const float* x      = (const float*)d_in[0];
  const int* ei0      = (const int*)d_in[1];
  const int* ei1      = (const int*)d_in[2];
  const int* batch    = (const int*)d_in[3];
  const float* p1w    = (const float*)d_in[4];
  const float* p1b    = (const float*)d_in[5];
  const float* as1r0  = (const float*)d_in[6];
  const float* ad1r0  = (const float*)d_in[7];
  const float* as1r1  = (const float*)d_in[8];
  const float* ad1r1  = (const float*)d_in[9];
  const float* kl1w   = (const float*)d_in[10];
  const float* kl1b   = (const float*)d_in[11];
  const float* q1     = (const float*)d_in[12];
  const float* p2w    = (const float*)d_in[13];
  const float* p2b    = (const float*)d_in[14];
  const float* as2r0  = (const float*)d_in[15];
  const float* ad2r0  = (const float*)d_in[16];
  const float* as2r1  = (const float*)d_in[17];
  const float* ad2r1  = (const float*)d_in[18];
  const float* kl2w   = (const float*)d_in[19];
  const float* kl2b   = (const float*)d_in[20];
  const float* q2     = (const float*)d_in[21];
  const float* d1w    = (const float*)d_in[22];
  const float* d1b    = (const float*)d_in[23];
  const float* bng    = (const float*)d_in[24];
  const float* bnb    = (const float*)d_in[25];
  const float* bnm    = (const float*)d_in[26];
  const float* bnv    = (const float*)d_in[27];
  const float* d2w    = (const float*)d_in[28];
  const float* d2b    = (const float*)d_in[29];
  float* out = (float*)d_out;

  const int N = in_sizes[3];       // 50000
  const int E = in_sizes[1] / 2;   // 400000
  const int G = 64;

  char* p = (char*)d_ws;
  auto alloc = [&](size_t bytes) -> void* {
    void* r = (void*)p;
    p += (bytes + 255) & ~(size_t)255;
    return r;
  };
  int* rp0    = (int*)alloc((N + 1) * sizeof(int));
  int* rp1    = (int*)alloc((N + 1) * sizeof(int));
  int* cs0    = (int*)alloc(E * sizeof(int));        // src per CSR slot
  int* cs1    = (int*)alloc(E * sizeof(int));
  int* deg    = (int*)alloc(2 * (size_t)N * sizeof(int));   // deg+cur: one memset
  int* cur    = (int*)alloc(2 * (size_t)N * sizeof(int));
  int* incl   = (int*)alloc(2 * (size_t)N * sizeof(int));
  int* bsum   = (int*)alloc(512 * sizeof(int));
  unsigned short* h_bf  = (unsigned short*)alloc((size_t)N * 256 * 2);
  unsigned short* st0   = (unsigned short*)alloc((size_t)N * 256 * 2);
  unsigned short* st1   = (unsigned short*)alloc((size_t)N * 256 * 2);
  unsigned short* h2_bf = (unsigned short*)alloc((size_t)N * 128 * 2);
  unsigned short* p1wt  = (unsigned short*)alloc(128 * 256 * 2);
  unsigned short* p2wt  = (unsigned short*)alloc(256 * 128 * 2);
  unsigned short* k1wt  = (unsigned short*)alloc(256 * 256 * 2);
  unsigned short* k2wt  = (unsigned short*)alloc(128 * 128 * 2);
  float* s0     = (float*)alloc((size_t)N * NHEAD * sizeof(float));
  float* d0     = (float*)alloc((size_t)N * NHEAD * sizeof(float));
  float* s1     = (float*)alloc((size_t)N * NHEAD * sizeof(float));
  float* d1     = (float*)alloc((size_t)N * NHEAD * sizeof(float));
  float* wslots = (float*)alloc((size_t)NSLOT * SLOT_STRIDE * sizeof(float));
  float* attn1  = (float*)alloc(2 * sizeof(float));
  float* attn2  = (float*)alloc(2 * sizeof(float));
  float* psum   = (float*)alloc((size_t)G * 128 * sizeof(float));

  // ---- 1: zero deg+cur (contiguous allocs -> single memset) ----
  size_t zlen = (size_t)((char*)cur - (char*)deg) + 2 * (size_t)N * sizeof(int);
  hipMemsetAsync(deg, 0, zlen, stream);

  // ---- 2: weight fragment-pack fused with dst histogram ----
  int wblk = 576;  // 147456 / 256
  int e2blk = (2 * E + 255) / 256;
  wtrans_hist_kernel<<<wblk + e2blk, 256, 0, stream>>>(
      p1w, p2w, kl1w, kl2w, p1wt, p2wt, k1wt, k2wt, ei0, ei1, E, deg, N, wblk);

  // ---- 3-6: scan + scatter ----
  int nb = (N + 255) / 256;
  scan_local2_kernel<<<2 * nb, 256, 0, stream>>>(deg, incl, bsum, N, nb);
  scan_bsum2_kernel<<<2, 256, 0, stream>>>(bsum, nb);
  scan_fix2_kernel<<<2 * nb, 256, 0, stream>>>(incl, deg, bsum, rp0, rp1, N, nb, E);
  scatter2_kernel<<<e2blk, 256, 0, stream>>>(ei0, ei1, E, rp0, rp1, cur, cs0, cs1, N);

  int gblk = (N + 63) / 64;
  int nblk4 = (N + 3) / 4;

  // ================= layer 1: 128 -> 256, D=64 =================
  mfma_gemm_proj<128, 256, 1, 64><<<gblk, 256, 0, stream>>>(
      x, nullptr, nullptr, nullptr, p1wt, p1b, h_bf,
      as1r0, ad1r0, as1r1, ad1r1, s0, d0, s1, d1, N);
  message2_kernel<256, 64><<<2 * nblk4, 256, 0, stream>>>(
      h_bf, cs0, rp0, s0, d0, st0, cs1, rp1, s1, d1, st1, wslots, N, nblk4);
  mfma_gemm_tanh2<256, 256><<<2 * gblk, 256, 0, stream>>>(
      st0, st1, k1wt, kl1b, wslots, N, gblk);
  attn_kernel<256, false><<<1, 256, 0, stream>>>(wslots, q1, attn1, 1.0f / (float)N,
                                                 nullptr, 0);

  // ================= layer 2: 256 -> 128, D=32 =================
  mfma_gemm_proj<256, 128, 2, 32><<<gblk, 256, 0, stream>>>(
      nullptr, st0, st1, attn1, p2wt, p2b, h2_bf,
      as2r0, ad2r0, as2r1, ad2r1, s0, d0, s1, d1, N);
  message2_kernel<128, 32><<<2 * nblk4, 256, 0, stream>>>(
      h2_bf, cs0, rp0, s0, d0, st0, cs1, rp1, s1, d1, st1, wslots, N, nblk4);
  mfma_gemm_tanh2<128, 128><<<2 * gblk, 256, 0, stream>>>(
      st0, st1, k2wt, kl2b, wslots, N, gblk);
  attn_kernel<128, true><<<1, 128, 0, stream>>>(wslots, q2, attn2, 1.0f / (float)N,
                                                psum, G * 128);

  // ---- pool (combine fused) + fused final/head ----
  int pblk = (N + PCH - 1) / PCH;
  pool_fused_kernel<<<pblk, 64, 0, stream>>>(st0, st1, attn2, batch, psum, N);
  poolhead_kernel<<<G, 128, 0, stream>>>(psum, batch, N, d1w, d1b, bng, bnb, bnm, bnv,
                                         d2w, d2b, out);
}

// Round 12
// 359.275 us; speedup vs baseline: 1.1427x; 1.0043x over previous
//
#include <hip/hip_runtime.h>
#include <math.h>

#define NHEAD 4
#define PCH 16
#define NSLOT 64
#define SLOT_STRIDE 512  // floats per slot (>= 2F for both layers)

typedef __bf16 bf16x8 __attribute__((ext_vector_type(8)));
typedef float f32x4 __attribute__((ext_vector_type(4)));

__device__ __forceinline__ unsigned short f2bf(float f) {
  unsigned int u = __float_as_uint(f);
  u += 0x7FFF + ((u >> 16) & 1);  // round-to-nearest-even
  return (unsigned short)(u >> 16);
}
__device__ __forceinline__ float bf2f(unsigned short s) {
  return __uint_as_float(((unsigned int)s) << 16);
}
__device__ __forceinline__ unsigned int comb2(unsigned int p, unsigned int q,
                                              float a0, float a1) {
  float lo = a0 * bf2f((unsigned short)p) + a1 * bf2f((unsigned short)q);
  float hi = a0 * bf2f((unsigned short)(p >> 16)) + a1 * bf2f((unsigned short)(q >> 16));
  return (unsigned)f2bf(lo) | ((unsigned)f2bf(hi) << 16);
}
__device__ __forceinline__ float fast_tanh(float x) {
  x = fminf(fmaxf(x, -15.f), 15.f);
  float e = __expf(2.f * x);
  return (e - 1.f) / (e + 1.f);
}

// ---- pack W[K][F] into MFMA-fragment order ----
__device__ __forceinline__ void pack_one(const float* __restrict__ W,
                                         unsigned short* __restrict__ out,
                                         int K, int F, int j) {
  int nkt = K >> 5;
  int chunk = nkt << 9;  // nkt*512
  int ft = j / chunk;
  int rem = j - ft * chunk;
  int kt = rem >> 9;
  int rem2 = rem & 511;
  int lane = rem2 >> 3;
  int jj = rem2 & 7;
  int k = (kt << 5) + ((lane >> 4) << 3) + jj;
  int f = (ft << 4) + (lane & 15);
  out[j] = f2bf(W[(size_t)k * F + f]);
}

// ============ combined: weight fragment-pack (blocks < wblk) + dst histogram ============
__global__ void wtrans_hist_kernel(const float* __restrict__ p1w, const float* __restrict__ p2w,
                                   const float* __restrict__ k1w, const float* __restrict__ k2w,
                                   unsigned short* __restrict__ p1wt,
                                   unsigned short* __restrict__ p2wt,
                                   unsigned short* __restrict__ k1wt,
                                   unsigned short* __restrict__ k2wt,
                                   const int* __restrict__ ei0, const int* __restrict__ ei1,
                                   int E, int* __restrict__ deg, int N, int wblk) {
  if ((int)blockIdx.x < wblk) {
    int i = blockIdx.x * 256 + threadIdx.x;
    if (i < 32768) {
      pack_one(p1w, p1wt, 128, 256, i);
    } else if (i < 65536) {
      pack_one(p2w, p2wt, 256, 128, i - 32768);
    } else if (i < 131072) {
      pack_one(k1w, k1wt, 256, 256, i - 65536);
    } else if (i < 147456) {
      pack_one(k2w, k2wt, 128, 128, i - 131072);
    }
  } else {
    int i = (blockIdx.x - wblk) * 256 + threadIdx.x;
    if (i < 2 * E) {
      int r = i >= E;
      int e = i - (r ? E : 0);
      const int* ei = r ? ei1 : ei0;
      atomicAdd(&deg[r * N + ei[E + e]], 1);
    }
  }
}

__global__ void scan_local2_kernel(const int* __restrict__ deg, int* __restrict__ incl,
                                   int* __restrict__ bsum, int n, int nb) {
  __shared__ int tile[256];
  int r = blockIdx.x / nb;
  int b = blockIdx.x - r * nb;
  int i = b * 256 + threadIdx.x;
  int v = (i < n) ? deg[r * n + i] : 0;
  tile[threadIdx.x] = v;
  __syncthreads();
  for (int off = 1; off < 256; off <<= 1) {
    int t = (threadIdx.x >= (unsigned)off) ? tile[threadIdx.x - off] : 0;
    __syncthreads();
    tile[threadIdx.x] += t;
    __syncthreads();
  }
  if (i < n) incl[r * n + i] = tile[threadIdx.x];
  if (threadIdx.x == 255) bsum[blockIdx.x] = tile[255];
}

__global__ void scan_bsum2_kernel(int* __restrict__ bsum, int nb) {
  __shared__ int tile[256];
  int r = blockIdx.x;
  int v = (threadIdx.x < (unsigned)nb) ? bsum[r * nb + threadIdx.x] : 0;
  tile[threadIdx.x] = v;
  __syncthreads();
  for (int off = 1; off < 256; off <<= 1) {
    int t = (threadIdx.x >= (unsigned)off) ? tile[threadIdx.x - off] : 0;
    __syncthreads();
    tile[threadIdx.x] += t;
    __syncthreads();
  }
  if (threadIdx.x < (unsigned)nb) bsum[r * nb + threadIdx.x] = tile[threadIdx.x] - v;
}

__global__ void scan_fix2_kernel(const int* __restrict__ incl, const int* __restrict__ deg,
                                 const int* __restrict__ bsum, int* __restrict__ rp0,
                                 int* __restrict__ rp1, int n, int nb, int E) {
  int r = blockIdx.x / nb;
  int b = blockIdx.x - r * nb;
  int i = b * 256 + threadIdx.x;
  int* rp = r ? rp1 : rp0;
  if (i < n) rp[i] = incl[r * n + i] - deg[r * n + i] + bsum[blockIdx.x];
  if (i == 0) rp[n] = E;
}

__global__ void scatter2_kernel(const int* __restrict__ ei0, const int* __restrict__ ei1,
                                int E, const int* __restrict__ rp0, const int* __restrict__ rp1,
                                int* __restrict__ cur, int* __restrict__ cs0,
                                int* __restrict__ cs1, int N) {
  int i = blockIdx.x * blockDim.x + threadIdx.x;
  int tot = 2 * E;
  for (; i < tot; i += gridDim.x * blockDim.x) {
    int r = i >= E;
    int e = i - (r ? E : 0);
    const int* ei = r ? ei1 : ei0;
    const int* rp = r ? rp1 : rp0;
    int* cs = r ? cs1 : cs0;
    int dst = ei[E + e];
    int pos = rp[dst] + atomicAdd(&cur[r * N + dst], 1);
    cs[pos] = ei[e];  // src node id
  }
}

// =============== MFMA GEMM core: 64 rows x F cols/block, 256 thr ===============
// A staged via double-buffered LDS (ONE barrier per k-step: write buf[kt&1],
// barrier, read — iter k+1's write lands after barrier k, so no read race).
// B from fragment-packed Wtp (one contiguous 1KB read per fragment).
#define MFMA_GEMM_CORE(K, F, BX)                                                      \
  constexpr int G = F / 64, S = 4 / G, RT = 4 / S;                                    \
  constexpr int NKT = K / 32;                                                         \
  __shared__ unsigned short As[2][64][40];                                            \
  const int tid = threadIdx.x;                                                        \
  const int lane = tid & 63, wid = tid >> 6;                                          \
  const int cg = wid % G, rg = wid / G;                                               \
  const int l15 = lane & 15, l4 = lane >> 4;                                          \
  const int m0 = (BX)*64;                                                             \
  const int wrow = rg * RT * 16;                                                      \
  f32x4 acc[RT][4];                                                                   \
  _Pragma("unroll") for (int rt = 0; rt < RT; ++rt)                                   \
  _Pragma("unroll") for (int ct = 0; ct < 4; ++ct)                                    \
      acc[rt][ct] = (f32x4){0.f, 0.f, 0.f, 0.f};                                      \
  const int arow = tid >> 2;                                                          \
  const int akk = (tid & 3) * 8;                                                      \
  for (int k0 = 0; k0 < K; k0 += 32) {                                                \
    const int kt = k0 >> 5;                                                           \
    uint4 av = {0u, 0u, 0u, 0u};                                                      \
    int row = m0 + arow;                                                              \
    if (row < M) { MFMA_LOAD_A }                                                      \
    *(uint4*)&As[kt & 1][arow][akk] = av;                                             \
    __syncthreads();                                                                  \
    bf16x8 bfr[4];                                                                    \
    _Pragma("unroll") for (int ct = 0; ct < 4; ++ct)                                  \
      bfr[ct] = *(const bf16x8*)&Wtp[((((cg * 4 + ct) * NKT + kt) * 64 + lane) << 3)];\
    _Pragma("unroll") for (int rt = 0; rt < RT; ++rt) {                               \
      bf16x8 afr = *(const bf16x8*)&As[kt & 1][wrow + rt * 16 + l15][l4 * 8];         \
      _Pragma("unroll") for (int ct = 0; ct < 4; ++ct)                                \
        acc[rt][ct] = __builtin_amdgcn_mfma_f32_16x16x32_bf16(                        \
            afr, bfr[ct], acc[rt][ct], 0, 0, 0);                                      \
    }                                                                                 \
  }

// ---- proj GEMM with fused bias store + s/d epilogue ----
template <int K, int F, int MODE, int DD>
__global__ __launch_bounds__(256) void mfma_gemm_proj(
    const float* __restrict__ Af,
    const unsigned short* __restrict__ S0, const unsigned short* __restrict__ S1,
    const float* __restrict__ attnp, const unsigned short* __restrict__ Wtp,
    const float* __restrict__ bias, unsigned short* __restrict__ out,
    const float* __restrict__ as0v, const float* __restrict__ ad0v,
    const float* __restrict__ as1v, const float* __restrict__ ad1v,
    float* __restrict__ s0g, float* __restrict__ d0g,
    float* __restrict__ s1g, float* __restrict__ d1g, int M) {
  float ca0 = 0.f, ca1 = 0.f;
  if constexpr (MODE == 2) { ca0 = attnp[0]; ca1 = attnp[1]; }
#define MFMA_LOAD_A                                                                   \
  if constexpr (MODE == 1) {                                                          \
    float4 f0 = *(const float4*)&Af[(size_t)row * K + k0 + akk];                      \
    float4 f1 = *(const float4*)&Af[(size_t)row * K + k0 + akk + 4];                  \
    av.x = (unsigned)f2bf(f0.x) | ((unsigned)f2bf(f0.y) << 16);                       \
    av.y = (unsigned)f2bf(f0.z) | ((unsigned)f2bf(f0.w) << 16);                       \
    av.z = (unsigned)f2bf(f1.x) | ((unsigned)f2bf(f1.y) << 16);                       \
    av.w = (unsigned)f2bf(f1.z) | ((unsigned)f2bf(f1.w) << 16);                       \
  } else {                                                                            \
    uint4 u0 = *(const uint4*)&S0[(size_t)row * K + k0 + akk];                        \
    uint4 u1 = *(const uint4*)&S1[(size_t)row * K + k0 + akk];                        \
    av.x = comb2(u0.x, u1.x, ca0, ca1);                                               \
    av.y = comb2(u0.y, u1.y, ca0, ca1);                                               \
    av.z = comb2(u0.z, u1.z, ca0, ca1);                                               \
    av.w = comb2(u0.w, u1.w, ca0, ca1);                                               \
  }
  MFMA_GEMM_CORE(K, F, blockIdx.x)
#undef MFMA_LOAD_A
  // ---- bf16 h store ----
#pragma unroll
  for (int ct = 0; ct < 4; ++ct) {
    int n = cg * 64 + ct * 16 + l15;
    float bv = bias[n];
#pragma unroll
    for (int rt = 0; rt < RT; ++rt)
#pragma unroll
      for (int r = 0; r < 4; ++r) {
        int m = m0 + wrow + rt * 16 + l4 * 4 + r;
        if (m < M) out[(size_t)m * F + n] = f2bf(acc[rt][ct][r] + bv);
      }
  }
  // ---- fused s/d epilogue: per-head column reductions ----
  constexpr int HPW = 64 / DD, CTH = DD / 16;
#pragma unroll
  for (int hw = 0; hw < HPW; ++hw) {
    int head = cg * HPW + hw;
    float a0v[CTH], a1v[CTH], a2v[CTH], a3v[CTH], bvv[CTH];
#pragma unroll
    for (int c = 0; c < CTH; ++c) {
      int col = cg * 64 + (hw * CTH + c) * 16 + l15;
      a0v[c] = as0v[col]; a1v[c] = ad0v[col];
      a2v[c] = as1v[col]; a3v[c] = ad1v[col];
      bvv[c] = bias[col];
    }
#pragma unroll
    for (int rt = 0; rt < RT; ++rt) {
#pragma unroll
      for (int r = 0; r < 4; ++r) {
        float v0 = 0.f, v1 = 0.f, v2 = 0.f, v3 = 0.f;
#pragma unroll
        for (int c = 0; c < CTH; ++c) {
          float hval = acc[rt][hw * CTH + c][r] + bvv[c];
          v0 += hval * a0v[c]; v1 += hval * a1v[c];
          v2 += hval * a2v[c]; v3 += hval * a3v[c];
        }
#pragma unroll
        for (int off = 8; off > 0; off >>= 1) {
          v0 += __shfl_xor(v0, off, 16);
          v1 += __shfl_xor(v1, off, 16);
          v2 += __shfl_xor(v2, off, 16);
          v3 += __shfl_xor(v3, off, 16);
        }
        if (l15 == 0) {
          int m = m0 + wrow + rt * 16 + l4 * 4 + r;
          if (m < M) {
            int idx = m * NHEAD + head;
            s0g[idx] = v0; d0g[idx] = v1;
            s1g[idx] = v2; d1g[idx] = v3;
          }
        }
      }
    }
  }
}

// ---- semantic GEMM, both relations in one launch: slot-spread atomics ----
template <int K, int F>
__global__ __launch_bounds__(256) void mfma_gemm_tanh2(
    const unsigned short* __restrict__ A0, const unsigned short* __restrict__ A1,
    const unsigned short* __restrict__ Wtp, const float* __restrict__ bias,
    float* __restrict__ wslots, int M, int half) {
  const unsigned short* A;
  float* ws = wslots + (blockIdx.x & (NSLOT - 1)) * SLOT_STRIDE;
  int bx = blockIdx.x;
  if (bx < half) { A = A0; }
  else { A = A1; ws += F; bx -= half; }
#define MFMA_LOAD_A av = *(const uint4*)&A[(size_t)row * K + k0 + akk];
  MFMA_GEMM_CORE(K, F, bx)
#undef MFMA_LOAD_A
#pragma unroll
  for (int ct = 0; ct < 4; ++ct) {
    int n = cg * 64 + ct * 16 + l15;
    float bv = bias[n];
    float cs = 0.f;
#pragma unroll
    for (int rt = 0; rt < RT; ++rt)
#pragma unroll
      for (int r = 0; r < 4; ++r) {
        int m = m0 + wrow + rt * 16 + l4 * 4 + r;
        if (m < M) cs += fast_tanh(acc[rt][ct][r] + bv);
      }
    cs += __shfl_xor(cs, 16, 64);
    cs += __shfl_xor(cs, 32, 64);
    if (l4 == 0) atomicAdd(&ws[n], cs);
  }
}

// ---- fused per-dst softmax + weighted gather + relu; wave/node, 8-edge unroll ----
__device__ __forceinline__ void acc4(uint2 hv, float v, float* acc) {
  acc[0] += v * bf2f((unsigned short)(hv.x & 0xffff));
  acc[1] += v * bf2f((unsigned short)(hv.x >> 16));
  acc[2] += v * bf2f((unsigned short)(hv.y & 0xffff));
  acc[3] += v * bf2f((unsigned short)(hv.y >> 16));
}
__device__ __forceinline__ void acc2(unsigned int hv, float v, float* acc) {
  acc[0] += v * bf2f((unsigned short)(hv & 0xffff));
  acc[1] += v * bf2f((unsigned short)(hv >> 16));
}
__device__ __forceinline__ float ecoef(float sv, float dv) {
  float a = sv + dv;
  a = (a >= 0.f) ? a : 0.2f * a;
  return __expf(a);  // segment_max skipped: cancels in softmax, alpha is O(1)
}

template <int F, int D>
__global__ void message2_kernel(const unsigned short* __restrict__ h,
                                const int* __restrict__ cs0, const int* __restrict__ rp0,
                                const float* __restrict__ s0, const float* __restrict__ d0,
                                unsigned short* __restrict__ o0,
                                const int* __restrict__ cs1, const int* __restrict__ rp1,
                                const float* __restrict__ s1, const float* __restrict__ d1,
                                unsigned short* __restrict__ o1,
                                float* __restrict__ wslots,  // blocks 0..63 zero slot b
                                int N, int half) {
  constexpr int VEC = F / 64;
  if (blockIdx.x < NSLOT) {
    float* ws = wslots + blockIdx.x * SLOT_STRIDE;
    for (int i = threadIdx.x; i < 2 * F; i += 256) ws[i] = 0.f;
  }
  int b = blockIdx.x;
  const int* colsrc; const int* rp; const float* s; const float* d;
  unsigned short* out;
  if (b < half) { colsrc = cs0; rp = rp0; s = s0; d = d0; out = o0; }
  else { b -= half; colsrc = cs1; rp = rp1; s = s1; d = d1; out = o1; }
  int w = threadIdx.x >> 6;
  int lane = threadIdx.x & 63;
  int nn = b * 4 + w;
  if (nn >= N) return;
  int f0 = lane * VEC;
  int hh = f0 / D;
  float dv = d[nn * NHEAD + hh];
  int lo = rp[nn], hi = rp[nn + 1];
  float acc[VEC];
#pragma unroll
  for (int v = 0; v < VEC; ++v) acc[v] = 0.f;
  float den = 0.f;
  int j = lo;
  // ---- 8-edge unrolled main loop (avg degree ~8 -> usually one pass) ----
  for (; j + 8 <= hi; j += 8) {
    int c[8];
#pragma unroll
    for (int u = 0; u < 8; ++u) c[u] = colsrc[j + u];
    float ee[8];
#pragma unroll
    for (int u = 0; u < 8; ++u) ee[u] = s[c[u] * NHEAD + hh];
    if constexpr (VEC == 4) {
      uint2 hv[8];
#pragma unroll
      for (int u = 0; u < 8; ++u) hv[u] = *(const uint2*)&h[(size_t)c[u] * F + f0];
#pragma unroll
      for (int u = 0; u < 8; ++u) {
        float v = ecoef(ee[u], dv);
        den += v;
        acc4(hv[u], v, acc);
      }
    } else {
      unsigned int hv[8];
#pragma unroll
      for (int u = 0; u < 8; ++u) hv[u] = *(const unsigned int*)&h[(size_t)c[u] * F + f0];
#pragma unroll
      for (int u = 0; u < 8; ++u) {
        float v = ecoef(ee[u], dv);
        den += v;
        acc2(hv[u], v, acc);
      }
    }
  }
  for (; j + 4 <= hi; j += 4) {
    int c0 = colsrc[j], c1 = colsrc[j + 1], c2 = colsrc[j + 2], c3 = colsrc[j + 3];
    float e0 = s[c0 * NHEAD + hh], e1 = s[c1 * NHEAD + hh];
    float e2 = s[c2 * NHEAD + hh], e3 = s[c3 * NHEAD + hh];
    if constexpr (VEC == 4) {
      uint2 h0 = *(const uint2*)&h[(size_t)c0 * F + f0];
      uint2 h1 = *(const uint2*)&h[(size_t)c1 * F + f0];
      uint2 h2 = *(const uint2*)&h[(size_t)c2 * F + f0];
      uint2 h3 = *(const uint2*)&h[(size_t)c3 * F + f0];
      float v0 = ecoef(e0, dv), v1 = ecoef(e1, dv);
      float v2 = ecoef(e2, dv), v3 = ecoef(e3, dv);
      den += v0 + v1 + v2 + v3;
      acc4(h0, v0, acc); acc4(h1, v1, acc);
      acc4(h2, v2, acc); acc4(h3, v3, acc);
    } else {
      unsigned int h0 = *(const unsigned int*)&h[(size_t)c0 * F + f0];
      unsigned int h1 = *(const unsigned int*)&h[(size_t)c1 * F + f0];
      unsigned int h2 = *(const unsigned int*)&h[(size_t)c2 * F + f0];
      unsigned int h3 = *(const unsigned int*)&h[(size_t)c3 * F + f0];
      float v0 = ecoef(e0, dv), v1 = ecoef(e1, dv);
      float v2 = ecoef(e2, dv), v3 = ecoef(e3, dv);
      den += v0 + v1 + v2 + v3;
      acc2(h0, v0, acc); acc2(h1, v1, acc);
      acc2(h2, v2, acc); acc2(h3, v3, acc);
    }
  }
  for (; j < hi; ++j) {
    int c = colsrc[j];
    float v = ecoef(s[c * NHEAD + hh], dv);
    den += v;
    if constexpr (VEC == 4) acc4(*(const uint2*)&h[(size_t)c * F + f0], v, acc);
    else acc2(*(const unsigned int*)&h[(size_t)c * F + f0], v, acc);
  }
  float inv = 1.f / (den + 1e-16f);
  if constexpr (VEC == 4) {
    uint2 o;
    o.x = (unsigned)f2bf(fmaxf(acc[0] * inv, 0.f)) |
          ((unsigned)f2bf(fmaxf(acc[1] * inv, 0.f)) << 16);
    o.y = (unsigned)f2bf(fmaxf(acc[2] * inv, 0.f)) |
          ((unsigned)f2bf(fmaxf(acc[3] * inv, 0.f)) << 16);
    *(uint2*)&out[(size_t)nn * F + f0] = o;
  } else {
    unsigned int o = (unsigned)f2bf(fmaxf(acc[0] * inv, 0.f)) |
                     ((unsigned)f2bf(fmaxf(acc[1] * inv, 0.f)) << 16);
    *(unsigned int*)&out[(size_t)nn * F + f0] = o;
  }
}

// ------- attn = softmax_r( mean_w_r . q ), reducing over NSLOT slots; opt zero psum -------
template <int F, bool ZP>
__global__ void attn_kernel(const float* __restrict__ wslots, const float* __restrict__ q,
                            float* __restrict__ attn, float inv_n,
                            float* __restrict__ psum, int pn) {
  __shared__ float red[2][F / 64];
  int f = threadIdx.x;
  if constexpr (ZP) {
    for (int i = f; i < pn; i += F) psum[i] = 0.f;
  }
  float w0 = 0.f, w1 = 0.f;
#pragma unroll 8
  for (int s = 0; s < NSLOT; ++s) {
    w0 += wslots[s * SLOT_STRIDE + f];
    w1 += wslots[s * SLOT_STRIDE + F + f];
  }
  float qv = q[f];
  float v0 = w0 * inv_n * qv;
  float v1 = w1 * inv_n * qv;
#pragma unroll
  for (int off = 32; off > 0; off >>= 1) {
    v0 += __shfl_down(v0, off, 64);
    v1 += __shfl_down(v1, off, 64);
  }
  int w = f / 64;
  if ((f & 63) == 0) { red[0][w] = v0; red[1][w] = v1; }
  __syncthreads();
  if (f == 0) {
    float d0 = 0.f, d1 = 0.f;
#pragma unroll
    for (int i = 0; i < F / 64; ++i) { d0 += red[0][i]; d1 += red[1][i]; }
    float m = fmaxf(d0, d1);
    float e0 = expf(d0 - m), e1 = expf(d1 - m);
    float inv = 1.f / (e0 + e1);
    attn[0] = e0 * inv;
    attn[1] = e1 * inv;
  }
}

// ------- pool with layer-2 combine fused (PCH=16 -> 3125 blocks, 1 wave each) -------
__global__ void pool_fused_kernel(const unsigned short* __restrict__ st0,
                                  const unsigned short* __restrict__ st1,
                                  const float* __restrict__ attn,
                                  const int* __restrict__ batch,
                                  float* __restrict__ psum, int n) {
  int c0 = blockIdx.x * PCH;
  if (c0 >= n) return;
  int lane = threadIdx.x;  // 64; 2 features each
  float a0 = attn[0], a1 = attn[1];
  int end = min(c0 + PCH, n);
  int g_cur = batch[c0];
  float acc0 = 0.f, acc1 = 0.f;
  for (int nn = c0; nn < end; ++nn) {
    int g = batch[nn];
    if (g != g_cur) {
      atomicAdd(&psum[g_cur * 128 + lane * 2], acc0);
      atomicAdd(&psum[g_cur * 128 + lane * 2 + 1], acc1);
      acc0 = acc1 = 0.f;
      g_cur = g;
    }
    unsigned int u0 = *(const unsigned int*)&st0[(size_t)nn * 128 + lane * 2];
    unsigned int u1 = *(const unsigned int*)&st1[(size_t)nn * 128 + lane * 2];
    acc0 += bf2f(f2bf(a0 * bf2f((unsigned short)(u0 & 0xffff)) +
                      a1 * bf2f((unsigned short)(u1 & 0xffff))));
    acc1 += bf2f(f2bf(a0 * bf2f((unsigned short)(u0 >> 16)) +
                      a1 * bf2f((unsigned short)(u1 >> 16))));
  }
  atomicAdd(&psum[g_cur * 128 + lane * 2], acc0);
  atomicAdd(&psum[g_cur * 128 + lane * 2 + 1], acc1);
}

__device__ __forceinline__ int lower_bound_i(const int* a, int n, int key) {
  int lo = 0, hi = n;
  while (lo < hi) {
    int mid = (lo + hi) >> 1;
    if (a[mid] < key) lo = mid + 1; else hi = mid;
  }
  return lo;
}

// ------- fused pool-final + MLP head: G blocks x 128 threads -------
__global__ void poolhead_kernel(const float* __restrict__ psum, const int* __restrict__ batch,
                                int n, const float* __restrict__ d1w,
                                const float* __restrict__ d1b, const float* __restrict__ gamma,
                                const float* __restrict__ beta, const float* __restrict__ mean,
                                const float* __restrict__ var, const float* __restrict__ d2w,
                                const float* __restrict__ d2b, float* __restrict__ out) {
  __shared__ float pool_sh[128];
  int g = blockIdx.x;
  int f = threadIdx.x;  // 128
  int lo = lower_bound_i(batch, n, g);
  int hi = lower_bound_i(batch, n, g + 1);
  float cnt = fmaxf((float)(hi - lo), 1.f);
  pool_sh[f] = psum[g * 128 + f] / cnt;
  __syncthreads();
  if (f < 64) {
    float acc = d1b[f];
#pragma unroll 8
    for (int k = 0; k < 128; ++k) acc += pool_sh[k] * d1w[k * 64 + f];
    float z = (acc - mean[f]) / sqrtf(var[f] + 1e-5f) * gamma[f] + beta[f];
    z = (z >= 0.f) ? z : 0.1f * z;
    float t = z * d2w[f];
#pragma unroll
    for (int off = 32; off > 0; off >>= 1) t += __shfl_down(t, off, 64);
    if (f == 0) out[g] = t + d2b[0];
  }
}

// =====================================================================
extern "C" void kernel_launch(void* const* d_in, const int* in_sizes, int n_in,
                              void* d_out, int out_size, void* d_ws, size_t ws_size,
                              hipStream_t stream) {
  const float* x      = (const float*)d_in[0];
  const int* ei0      = (const int*)d_in[1];
  const int* ei1      = (const int*)d_in[2];
  const int* batch    = (const int*)d_in[3];
  const float* p1w    = (const float*)d_in[4];
  const float* p1b    = (const float*)d_in[5];
  const float* as1r0  = (const float*)d_in[6];
  const float* ad1r0  = (const float*)d_in[7];
  const float* as1r1  = (const float*)d_in[8];
  const float* ad1r1  = (const float*)d_in[9];
  const float* kl1w   = (const float*)d_in[10];
  const float* kl1b   = (const float*)d_in[11];
  const float* q1     = (const float*)d_in[12];
  const float* p2w    = (const float*)d_in[13];
  const float* p2b    = (const float*)d_in[14];
  const float* as2r0  = (const float*)d_in[15];
  const float* ad2r0  = (const float*)d_in[16];
  const float* as2r1  = (const float*)d_in[17];
  const float* ad2r1  = (const float*)d_in[18];
  const float* kl2w   = (const float*)d_in[19];
  const float* kl2b   = (const float*)d_in[20];
  const float* q2     = (const float*)d_in[21];
  const float* d1w    = (const float*)d_in[22];
  const float* d1b    = (const float*)d_in[23];
  const float* bng    = (const float*)d_in[24];
  const float* bnb    = (const float*)d_in[25];
  const float* bnm    = (const float*)d_in[26];
  const float* bnv    = (const float*)d_in[27];
  const float* d2w    = (const float*)d_in[28];
  const float* d2b    = (const float*)d_in[29];
  float* out = (float*)d_out;

  const int N = in_sizes[3];       // 50000
  const int E = in_sizes[1] / 2;   // 400000
  const int G = 64;

  char* p = (char*)d_ws;
  auto alloc = [&](size_t bytes) -> void* {
    void* r = (void*)p;
    p += (bytes + 255) & ~(size_t)255;
    return r;
  };
  int* rp0    = (int*)alloc((N + 1) * sizeof(int));
  int* rp1    = (int*)alloc((N + 1) * sizeof(int));
  int* cs0    = (int*)alloc(E * sizeof(int));        // src per CSR slot
  int* cs1    = (int*)alloc(E * sizeof(int));
  int* deg    = (int*)alloc(2 * (size_t)N * sizeof(int));   // deg+cur: one memset
  int* cur    = (int*)alloc(2 * (size_t)N * sizeof(int));
  int* incl   = (int*)alloc(2 * (size_t)N * sizeof(int));
  int* bsum   = (int*)alloc(512 * sizeof(int));
  unsigned short* h_bf  = (unsigned short*)alloc((size_t)N * 256 * 2);
  unsigned short* st0   = (unsigned short*)alloc((size_t)N * 256 * 2);
  unsigned short* st1   = (unsigned short*)alloc((size_t)N * 256 * 2);
  unsigned short* h2_bf = (unsigned short*)alloc((size_t)N * 128 * 2);
  unsigned short* p1wt  = (unsigned short*)alloc(128 * 256 * 2);
  unsigned short* p2wt  = (unsigned short*)alloc(256 * 128 * 2);
  unsigned short* k1wt  = (unsigned short*)alloc(256 * 256 * 2);
  unsigned short* k2wt  = (unsigned short*)alloc(128 * 128 * 2);
  float* s0     = (float*)alloc((size_t)N * NHEAD * sizeof(float));
  float* d0     = (float*)alloc((size_t)N * NHEAD * sizeof(float));
  float* s1     = (float*)alloc((size_t)N * NHEAD * sizeof(float));
  float* d1     = (float*)alloc((size_t)N * NHEAD * sizeof(float));
  float* wslots = (float*)alloc((size_t)NSLOT * SLOT_STRIDE * sizeof(float));
  float* attn1  = (float*)alloc(2 * sizeof(float));
  float* attn2  = (float*)alloc(2 * sizeof(float));
  float* psum   = (float*)alloc((size_t)G * 128 * sizeof(float));

  // ---- 1: zero deg+cur (contiguous allocs -> single memset) ----
  size_t zlen = (size_t)((char*)cur - (char*)deg) + 2 * (size_t)N * sizeof(int);
  hipMemsetAsync(deg, 0, zlen, stream);

  // ---- 2: weight fragment-pack fused with dst histogram ----
  int wblk = 576;  // 147456 / 256
  int e2blk = (2 * E + 255) / 256;
  wtrans_hist_kernel<<<wblk + e2blk, 256, 0, stream>>>(
      p1w, p2w, kl1w, kl2w, p1wt, p2wt, k1wt, k2wt, ei0, ei1, E, deg, N, wblk);

  // ---- 3-6: scan + scatter ----
  int nb = (N + 255) / 256;
  scan_local2_kernel<<<2 * nb, 256, 0, stream>>>(deg, incl, bsum, N, nb);
  scan_bsum2_kernel<<<2, 256, 0, stream>>>(bsum, nb);
  scan_fix2_kernel<<<2 * nb, 256, 0, stream>>>(incl, deg, bsum, rp0, rp1, N, nb, E);
  scatter2_kernel<<<e2blk, 256, 0, stream>>>(ei0, ei1, E, rp0, rp1, cur, cs0, cs1, N);

  int gblk = (N + 63) / 64;
  int nblk4 = (N + 3) / 4;

  // ================= layer 1: 128 -> 256, D=64 =================
  mfma_gemm_proj<128, 256, 1, 64><<<gblk, 256, 0, stream>>>(
      x, nullptr, nullptr, nullptr, p1wt, p1b, h_bf,
      as1r0, ad1r0, as1r1, ad1r1, s0, d0, s1, d1, N);
  message2_kernel<256, 64><<<2 * nblk4, 256, 0, stream>>>(
      h_bf, cs0, rp0, s0, d0, st0, cs1, rp1, s1, d1, st1, wslots, N, nblk4);
  mfma_gemm_tanh2<256, 256><<<2 * gblk, 256, 0, stream>>>(
      st0, st1, k1wt, kl1b, wslots, N, gblk);
  attn_kernel<256, false><<<1, 256, 0, stream>>>(wslots, q1, attn1, 1.0f / (float)N,
                                                 nullptr, 0);

  // ================= layer 2: 256 -> 128, D=32 =================
  mfma_gemm_proj<256, 128, 2, 32><<<gblk, 256, 0, stream>>>(
      nullptr, st0, st1, attn1, p2wt, p2b, h2_bf,
      as2r0, ad2r0, as2r1, ad2r1, s0, d0, s1, d1, N);
  message2_kernel<128, 32><<<2 * nblk4, 256, 0, stream>>>(
      h2_bf, cs0, rp0, s0, d0, st0, cs1, rp1, s1, d1, st1, wslots, N, nblk4);
  mfma_gemm_tanh2<128, 128><<<2 * gblk, 256, 0, stream>>>(
      st0, st1, k2wt, kl2b, wslots, N, gblk);
  attn_kernel<128, true><<<1, 128, 0, stream>>>(wslots, q2, attn2, 1.0f / (float)N,
                                                psum, G * 128);

  // ---- pool (combine fused) + fused final/head ----
  int pblk = (N + PCH - 1) / PCH;
  pool_fused_kernel<<<pblk, 64, 0, stream>>>(st0, st1, attn2, batch, psum, N);
  poolhead_kernel<<<G, 128, 0, stream>>>(psum, batch, N, d1w, d1b, bng, bnb, bnm, bnv,
                                         d2w, d2b, out);
}

// Round 13
// 350.610 us; speedup vs baseline: 1.1709x; 1.0247x over previous
//
#include <hip/hip_runtime.h>
#include <math.h>

#define NHEAD 4
#define PCH 16
#define NSLOT 64
#define SLOT_STRIDE 512  // floats per slot (>= 2F for both layers)

typedef __bf16 bf16x8 __attribute__((ext_vector_type(8)));
typedef float f32x4 __attribute__((ext_vector_type(4)));

__device__ __forceinline__ unsigned short f2bf(float f) {
  unsigned int u = __float_as_uint(f);
  u += 0x7FFF + ((u >> 16) & 1);  // round-to-nearest-even
  return (unsigned short)(u >> 16);
}
__device__ __forceinline__ float bf2f(unsigned short s) {
  return __uint_as_float(((unsigned int)s) << 16);
}
__device__ __forceinline__ unsigned int comb2(unsigned int p, unsigned int q,
                                              float a0, float a1) {
  float lo = a0 * bf2f((unsigned short)p) + a1 * bf2f((unsigned short)q);
  float hi = a0 * bf2f((unsigned short)(p >> 16)) + a1 * bf2f((unsigned short)(q >> 16));
  return (unsigned)f2bf(lo) | ((unsigned)f2bf(hi) << 16);
}
__device__ __forceinline__ float fast_tanh(float x) {
  x = fminf(fmaxf(x, -15.f), 15.f);
  float e = __expf(2.f * x);
  return (e - 1.f) / (e + 1.f);
}

// ---- pack W[K][F] into MFMA-fragment order ----
__device__ __forceinline__ void pack_one(const float* __restrict__ W,
                                         unsigned short* __restrict__ out,
                                         int K, int F, int j) {
  int nkt = K >> 5;
  int chunk = nkt << 9;  // nkt*512
  int ft = j / chunk;
  int rem = j - ft * chunk;
  int kt = rem >> 9;
  int rem2 = rem & 511;
  int lane = rem2 >> 3;
  int jj = rem2 & 7;
  int k = (kt << 5) + ((lane >> 4) << 3) + jj;
  int f = (ft << 4) + (lane & 15);
  out[j] = f2bf(W[(size_t)k * F + f]);
}

// ============ combined: weight fragment-pack (blocks < wblk) + dst histogram ============
__global__ void wtrans_hist_kernel(const float* __restrict__ p1w, const float* __restrict__ p2w,
                                   const float* __restrict__ k1w, const float* __restrict__ k2w,
                                   unsigned short* __restrict__ p1wt,
                                   unsigned short* __restrict__ p2wt,
                                   unsigned short* __restrict__ k1wt,
                                   unsigned short* __restrict__ k2wt,
                                   const int* __restrict__ ei0, const int* __restrict__ ei1,
                                   int E, int* __restrict__ deg, int N, int wblk) {
  if ((int)blockIdx.x < wblk) {
    int i = blockIdx.x * 256 + threadIdx.x;
    if (i < 32768) {
      pack_one(p1w, p1wt, 128, 256, i);
    } else if (i < 65536) {
      pack_one(p2w, p2wt, 256, 128, i - 32768);
    } else if (i < 131072) {
      pack_one(k1w, k1wt, 256, 256, i - 65536);
    } else if (i < 147456) {
      pack_one(k2w, k2wt, 128, 128, i - 131072);
    }
  } else {
    int i = (blockIdx.x - wblk) * 256 + threadIdx.x;
    if (i < 2 * E) {
      int r = i >= E;
      int e = i - (r ? E : 0);
      const int* ei = r ? ei1 : ei0;
      atomicAdd(&deg[r * N + ei[E + e]], 1);
    }
  }
}

__global__ void scan_local2_kernel(const int* __restrict__ deg, int* __restrict__ incl,
                                   int* __restrict__ bsum, int n, int nb) {
  __shared__ int tile[256];
  int r = blockIdx.x / nb;
  int b = blockIdx.x - r * nb;
  int i = b * 256 + threadIdx.x;
  int v = (i < n) ? deg[r * n + i] : 0;
  tile[threadIdx.x] = v;
  __syncthreads();
  for (int off = 1; off < 256; off <<= 1) {
    int t = (threadIdx.x >= (unsigned)off) ? tile[threadIdx.x - off] : 0;
    __syncthreads();
    tile[threadIdx.x] += t;
    __syncthreads();
  }
  if (i < n) incl[r * n + i] = tile[threadIdx.x];
  if (threadIdx.x == 255) bsum[blockIdx.x] = tile[255];
}

__global__ void scan_bsum2_kernel(int* __restrict__ bsum, int nb) {
  __shared__ int tile[256];
  int r = blockIdx.x;
  int v = (threadIdx.x < (unsigned)nb) ? bsum[r * nb + threadIdx.x] : 0;
  tile[threadIdx.x] = v;
  __syncthreads();
  for (int off = 1; off < 256; off <<= 1) {
    int t = (threadIdx.x >= (unsigned)off) ? tile[threadIdx.x - off] : 0;
    __syncthreads();
    tile[threadIdx.x] += t;
    __syncthreads();
  }
  if (threadIdx.x < (unsigned)nb) bsum[r * nb + threadIdx.x] = tile[threadIdx.x] - v;
}

__global__ void scan_fix2_kernel(const int* __restrict__ incl, const int* __restrict__ deg,
                                 const int* __restrict__ bsum, int* __restrict__ rp0,
                                 int* __restrict__ rp1, int n, int nb, int E) {
  int r = blockIdx.x / nb;
  int b = blockIdx.x - r * nb;
  int i = b * 256 + threadIdx.x;
  int* rp = r ? rp1 : rp0;
  if (i < n) rp[i] = incl[r * n + i] - deg[r * n + i] + bsum[blockIdx.x];
  if (i == 0) rp[n] = E;
}

__global__ void scatter2_kernel(const int* __restrict__ ei0, const int* __restrict__ ei1,
                                int E, const int* __restrict__ rp0, const int* __restrict__ rp1,
                                int* __restrict__ cur, int* __restrict__ cs0,
                                int* __restrict__ cs1, int N) {
  int i = blockIdx.x * blockDim.x + threadIdx.x;
  int tot = 2 * E;
  for (; i < tot; i += gridDim.x * blockDim.x) {
    int r = i >= E;
    int e = i - (r ? E : 0);
    const int* ei = r ? ei1 : ei0;
    const int* rp = r ? rp1 : rp0;
    int* cs = r ? cs1 : cs0;
    int dst = ei[E + e];
    int pos = rp[dst] + atomicAdd(&cur[r * N + dst], 1);
    cs[pos] = ei[e];  // src node id
  }
}

// =============== MFMA GEMM core: 64 rows x F cols/block, 256 thr ===============
// Double-buffered LDS + REGISTER PREFETCH: the global A-load for k-step t+1 is
// issued right after barrier t, consumed at step t+1's LDS write -> its latency
// hides under step t's B-loads + 16 MFMAs and other waves. One barrier/step;
// buf[t&1] rewrite at t+2 is fenced from step-t reads by barrier t+1.
#define MFMA_GEMM_CORE(K, F, BX)                                                      \
  constexpr int G = F / 64, S = 4 / G, RT = 4 / S;                                    \
  constexpr int NKT = K / 32;                                                         \
  __shared__ unsigned short As[2][64][40];                                            \
  const int tid = threadIdx.x;                                                        \
  const int lane = tid & 63, wid = tid >> 6;                                          \
  const int cg = wid % G, rg = wid / G;                                               \
  const int l15 = lane & 15, l4 = lane >> 4;                                          \
  const int m0 = (BX)*64;                                                             \
  const int wrow = rg * RT * 16;                                                      \
  f32x4 acc[RT][4];                                                                   \
  _Pragma("unroll") for (int rt = 0; rt < RT; ++rt)                                   \
  _Pragma("unroll") for (int ct = 0; ct < 4; ++ct)                                    \
      acc[rt][ct] = (f32x4){0.f, 0.f, 0.f, 0.f};                                      \
  const int arow = tid >> 2;                                                          \
  const int akk = (tid & 3) * 8;                                                      \
  const int row = m0 + arow;                                                          \
  uint4 av = {0u, 0u, 0u, 0u};                                                        \
  { const int k0 = 0; if (row < M) { MFMA_LOAD_A } }                                  \
  for (int kt = 0; kt < NKT; ++kt) {                                                  \
    *(uint4*)&As[kt & 1][arow][akk] = av;                                             \
    __syncthreads();                                                                  \
    if (kt + 1 < NKT) {                                                               \
      const int k0 = (kt + 1) * 32;                                                   \
      av = (uint4){0u, 0u, 0u, 0u};                                                   \
      if (row < M) { MFMA_LOAD_A }                                                    \
    }                                                                                 \
    bf16x8 bfr[4];                                                                    \
    _Pragma("unroll") for (int ct = 0; ct < 4; ++ct)                                  \
      bfr[ct] = *(const bf16x8*)&Wtp[((((cg * 4 + ct) * NKT + kt) * 64 + lane) << 3)];\
    _Pragma("unroll") for (int rt = 0; rt < RT; ++rt) {                               \
      bf16x8 afr = *(const bf16x8*)&As[kt & 1][wrow + rt * 16 + l15][l4 * 8];         \
      _Pragma("unroll") for (int ct = 0; ct < 4; ++ct)                                \
        acc[rt][ct] = __builtin_amdgcn_mfma_f32_16x16x32_bf16(                        \
            afr, bfr[ct], acc[rt][ct], 0, 0, 0);                                      \
    }                                                                                 \
  }

// ---- proj GEMM with fused bias store + s/d epilogue ----
template <int K, int F, int MODE, int DD>
__global__ __launch_bounds__(256) void mfma_gemm_proj(
    const float* __restrict__ Af,
    const unsigned short* __restrict__ S0, const unsigned short* __restrict__ S1,
    const float* __restrict__ attnp, const unsigned short* __restrict__ Wtp,
    const float* __restrict__ bias, unsigned short* __restrict__ out,
    const float* __restrict__ as0v, const float* __restrict__ ad0v,
    const float* __restrict__ as1v, const float* __restrict__ ad1v,
    float* __restrict__ s0g, float* __restrict__ d0g,
    float* __restrict__ s1g, float* __restrict__ d1g, int M) {
  float ca0 = 0.f, ca1 = 0.f;
  if constexpr (MODE == 2) { ca0 = attnp[0]; ca1 = attnp[1]; }
#define MFMA_LOAD_A                                                                   \
  if constexpr (MODE == 1) {                                                          \
    float4 f0 = *(const float4*)&Af[(size_t)row * K + k0 + akk];                      \
    float4 f1 = *(const float4*)&Af[(size_t)row * K + k0 + akk + 4];                  \
    av.x = (unsigned)f2bf(f0.x) | ((unsigned)f2bf(f0.y) << 16);                       \
    av.y = (unsigned)f2bf(f0.z) | ((unsigned)f2bf(f0.w) << 16);                       \
    av.z = (unsigned)f2bf(f1.x) | ((unsigned)f2bf(f1.y) << 16);                       \
    av.w = (unsigned)f2bf(f1.z) | ((unsigned)f2bf(f1.w) << 16);                       \
  } else {                                                                            \
    uint4 u0 = *(const uint4*)&S0[(size_t)row * K + k0 + akk];                        \
    uint4 u1 = *(const uint4*)&S1[(size_t)row * K + k0 + akk];                        \
    av.x = comb2(u0.x, u1.x, ca0, ca1);                                               \
    av.y = comb2(u0.y, u1.y, ca0, ca1);                                               \
    av.z = comb2(u0.z, u1.z, ca0, ca1);                                               \
    av.w = comb2(u0.w, u1.w, ca0, ca1);                                               \
  }
  MFMA_GEMM_CORE(K, F, blockIdx.x)
#undef MFMA_LOAD_A
  // ---- bf16 h store ----
#pragma unroll
  for (int ct = 0; ct < 4; ++ct) {
    int n = cg * 64 + ct * 16 + l15;
    float bv = bias[n];
#pragma unroll
    for (int rt = 0; rt < RT; ++rt)
#pragma unroll
      for (int r = 0; r < 4; ++r) {
        int m = m0 + wrow + rt * 16 + l4 * 4 + r;
        if (m < M) out[(size_t)m * F + n] = f2bf(acc[rt][ct][r] + bv);
      }
  }
  // ---- fused s/d epilogue: per-head column reductions ----
  constexpr int HPW = 64 / DD, CTH = DD / 16;
#pragma unroll
  for (int hw = 0; hw < HPW; ++hw) {
    int head = cg * HPW + hw;
    float a0v[CTH], a1v[CTH], a2v[CTH], a3v[CTH], bvv[CTH];
#pragma unroll
    for (int c = 0; c < CTH; ++c) {
      int col = cg * 64 + (hw * CTH + c) * 16 + l15;
      a0v[c] = as0v[col]; a1v[c] = ad0v[col];
      a2v[c] = as1v[col]; a3v[c] = ad1v[col];
      bvv[c] = bias[col];
    }
#pragma unroll
    for (int rt = 0; rt < RT; ++rt) {
#pragma unroll
      for (int r = 0; r < 4; ++r) {
        float v0 = 0.f, v1 = 0.f, v2 = 0.f, v3 = 0.f;
#pragma unroll
        for (int c = 0; c < CTH; ++c) {
          float hval = acc[rt][hw * CTH + c][r] + bvv[c];
          v0 += hval * a0v[c]; v1 += hval * a1v[c];
          v2 += hval * a2v[c]; v3 += hval * a3v[c];
        }
#pragma unroll
        for (int off = 8; off > 0; off >>= 1) {
          v0 += __shfl_xor(v0, off, 16);
          v1 += __shfl_xor(v1, off, 16);
          v2 += __shfl_xor(v2, off, 16);
          v3 += __shfl_xor(v3, off, 16);
        }
        if (l15 == 0) {
          int m = m0 + wrow + rt * 16 + l4 * 4 + r;
          if (m < M) {
            int idx = m * NHEAD + head;
            s0g[idx] = v0; d0g[idx] = v1;
            s1g[idx] = v2; d1g[idx] = v3;
          }
        }
      }
    }
  }
}

// ---- semantic GEMM, both relations in one launch: slot-spread atomics ----
template <int K, int F>
__global__ __launch_bounds__(256) void mfma_gemm_tanh2(
    const unsigned short* __restrict__ A0, const unsigned short* __restrict__ A1,
    const unsigned short* __restrict__ Wtp, const float* __restrict__ bias,
    float* __restrict__ wslots, int M, int half) {
  const unsigned short* A;
  float* ws = wslots + (blockIdx.x & (NSLOT - 1)) * SLOT_STRIDE;
  int bx = blockIdx.x;
  if (bx < half) { A = A0; }
  else { A = A1; ws += F; bx -= half; }
#define MFMA_LOAD_A av = *(const uint4*)&A[(size_t)row * K + k0 + akk];
  MFMA_GEMM_CORE(K, F, bx)
#undef MFMA_LOAD_A
#pragma unroll
  for (int ct = 0; ct < 4; ++ct) {
    int n = cg * 64 + ct * 16 + l15;
    float bv = bias[n];
    float cs = 0.f;
#pragma unroll
    for (int rt = 0; rt < RT; ++rt)
#pragma unroll
      for (int r = 0; r < 4; ++r) {
        int m = m0 + wrow + rt * 16 + l4 * 4 + r;
        if (m < M) cs += fast_tanh(acc[rt][ct][r] + bv);
      }
    cs += __shfl_xor(cs, 16, 64);
    cs += __shfl_xor(cs, 32, 64);
    if (l4 == 0) atomicAdd(&ws[n], cs);
  }
}

// ---- fused per-dst softmax + weighted gather + relu; wave/node, 8-edge unroll ----
__device__ __forceinline__ void acc4(uint2 hv, float v, float* acc) {
  acc[0] += v * bf2f((unsigned short)(hv.x & 0xffff));
  acc[1] += v * bf2f((unsigned short)(hv.x >> 16));
  acc[2] += v * bf2f((unsigned short)(hv.y & 0xffff));
  acc[3] += v * bf2f((unsigned short)(hv.y >> 16));
}
__device__ __forceinline__ void acc2(unsigned int hv, float v, float* acc) {
  acc[0] += v * bf2f((unsigned short)(hv & 0xffff));
  acc[1] += v * bf2f((unsigned short)(hv >> 16));
}
__device__ __forceinline__ float ecoef(float sv, float dv) {
  float a = sv + dv;
  a = (a >= 0.f) ? a : 0.2f * a;
  return __expf(a);  // segment_max skipped: cancels in softmax, alpha is O(1)
}

template <int F, int D>
__global__ void message2_kernel(const unsigned short* __restrict__ h,
                                const int* __restrict__ cs0, const int* __restrict__ rp0,
                                const float* __restrict__ s0, const float* __restrict__ d0,
                                unsigned short* __restrict__ o0,
                                const int* __restrict__ cs1, const int* __restrict__ rp1,
                                const float* __restrict__ s1, const float* __restrict__ d1,
                                unsigned short* __restrict__ o1,
                                float* __restrict__ wslots,  // blocks 0..63 zero slot b
                                int N, int half) {
  constexpr int VEC = F / 64;
  if (blockIdx.x < NSLOT) {
    float* ws = wslots + blockIdx.x * SLOT_STRIDE;
    for (int i = threadIdx.x; i < 2 * F; i += 256) ws[i] = 0.f;
  }
  int b = blockIdx.x;
  const int* colsrc; const int* rp; const float* s; const float* d;
  unsigned short* out;
  if (b < half) { colsrc = cs0; rp = rp0; s = s0; d = d0; out = o0; }
  else { b -= half; colsrc = cs1; rp = rp1; s = s1; d = d1; out = o1; }
  int w = threadIdx.x >> 6;
  int lane = threadIdx.x & 63;
  int nn = b * 4 + w;
  if (nn >= N) return;
  int f0 = lane * VEC;
  int hh = f0 / D;
  float dv = d[nn * NHEAD + hh];
  int lo = rp[nn], hi = rp[nn + 1];
  float acc[VEC];
#pragma unroll
  for (int v = 0; v < VEC; ++v) acc[v] = 0.f;
  float den = 0.f;
  int j = lo;
  for (; j + 8 <= hi; j += 8) {
    int c[8];
#pragma unroll
    for (int u = 0; u < 8; ++u) c[u] = colsrc[j + u];
    float ee[8];
#pragma unroll
    for (int u = 0; u < 8; ++u) ee[u] = s[c[u] * NHEAD + hh];
    if constexpr (VEC == 4) {
      uint2 hv[8];
#pragma unroll
      for (int u = 0; u < 8; ++u) hv[u] = *(const uint2*)&h[(size_t)c[u] * F + f0];
#pragma unroll
      for (int u = 0; u < 8; ++u) {
        float v = ecoef(ee[u], dv);
        den += v;
        acc4(hv[u], v, acc);
      }
    } else {
      unsigned int hv[8];
#pragma unroll
      for (int u = 0; u < 8; ++u) hv[u] = *(const unsigned int*)&h[(size_t)c[u] * F + f0];
#pragma unroll
      for (int u = 0; u < 8; ++u) {
        float v = ecoef(ee[u], dv);
        den += v;
        acc2(hv[u], v, acc);
      }
    }
  }
  for (; j + 4 <= hi; j += 4) {
    int c0 = colsrc[j], c1 = colsrc[j + 1], c2 = colsrc[j + 2], c3 = colsrc[j + 3];
    float e0 = s[c0 * NHEAD + hh], e1 = s[c1 * NHEAD + hh];
    float e2 = s[c2 * NHEAD + hh], e3 = s[c3 * NHEAD + hh];
    if constexpr (VEC == 4) {
      uint2 h0 = *(const uint2*)&h[(size_t)c0 * F + f0];
      uint2 h1 = *(const uint2*)&h[(size_t)c1 * F + f0];
      uint2 h2 = *(const uint2*)&h[(size_t)c2 * F + f0];
      uint2 h3 = *(const uint2*)&h[(size_t)c3 * F + f0];
      float v0 = ecoef(e0, dv), v1 = ecoef(e1, dv);
      float v2 = ecoef(e2, dv), v3 = ecoef(e3, dv);
      den += v0 + v1 + v2 + v3;
      acc4(h0, v0, acc); acc4(h1, v1, acc);
      acc4(h2, v2, acc); acc4(h3, v3, acc);
    } else {
      unsigned int h0 = *(const unsigned int*)&h[(size_t)c0 * F + f0];
      unsigned int h1 = *(const unsigned int*)&h[(size_t)c1 * F + f0];
      unsigned int h2 = *(const unsigned int*)&h[(size_t)c2 * F + f0];
      unsigned int h3 = *(const unsigned int*)&h[(size_t)c3 * F + f0];
      float v0 = ecoef(e0, dv), v1 = ecoef(e1, dv);
      float v2 = ecoef(e2, dv), v3 = ecoef(e3, dv);
      den += v0 + v1 + v2 + v3;
      acc2(h0, v0, acc); acc2(h1, v1, acc);
      acc2(h2, v2, acc); acc2(h3, v3, acc);
    }
  }
  for (; j < hi; ++j) {
    int c = colsrc[j];
    float v = ecoef(s[c * NHEAD + hh], dv);
    den += v;
    if constexpr (VEC == 4) acc4(*(const uint2*)&h[(size_t)c * F + f0], v, acc);
    else acc2(*(const unsigned int*)&h[(size_t)c * F + f0], v, acc);
  }
  float inv = 1.f / (den + 1e-16f);
  if constexpr (VEC == 4) {
    uint2 o;
    o.x = (unsigned)f2bf(fmaxf(acc[0] * inv, 0.f)) |
          ((unsigned)f2bf(fmaxf(acc[1] * inv, 0.f)) << 16);
    o.y = (unsigned)f2bf(fmaxf(acc[2] * inv, 0.f)) |
          ((unsigned)f2bf(fmaxf(acc[3] * inv, 0.f)) << 16);
    *(uint2*)&out[(size_t)nn * F + f0] = o;
  } else {
    unsigned int o = (unsigned)f2bf(fmaxf(acc[0] * inv, 0.f)) |
                     ((unsigned)f2bf(fmaxf(acc[1] * inv, 0.f)) << 16);
    *(unsigned int*)&out[(size_t)nn * F + f0] = o;
  }
}

// ------- attn = softmax_r( mean_w_r . q ), reducing over NSLOT slots; opt zero psum -------
template <int F, bool ZP>
__global__ void attn_kernel(const float* __restrict__ wslots, const float* __restrict__ q,
                            float* __restrict__ attn, float inv_n,
                            float* __restrict__ psum, int pn) {
  __shared__ float red[2][F / 64];
  int f = threadIdx.x;
  if constexpr (ZP) {
    for (int i = f; i < pn; i += F) psum[i] = 0.f;
  }
  float w0 = 0.f, w1 = 0.f;
#pragma unroll 8
  for (int s = 0; s < NSLOT; ++s) {
    w0 += wslots[s * SLOT_STRIDE + f];
    w1 += wslots[s * SLOT_STRIDE + F + f];
  }
  float qv = q[f];
  float v0 = w0 * inv_n * qv;
  float v1 = w1 * inv_n * qv;
#pragma unroll
  for (int off = 32; off > 0; off >>= 1) {
    v0 += __shfl_down(v0, off, 64);
    v1 += __shfl_down(v1, off, 64);
  }
  int w = f / 64;
  if ((f & 63) == 0) { red[0][w] = v0; red[1][w] = v1; }
  __syncthreads();
  if (f == 0) {
    float d0 = 0.f, d1 = 0.f;
#pragma unroll
    for (int i = 0; i < F / 64; ++i) { d0 += red[0][i]; d1 += red[1][i]; }
    float m = fmaxf(d0, d1);
    float e0 = expf(d0 - m), e1 = expf(d1 - m);
    float inv = 1.f / (e0 + e1);
    attn[0] = e0 * inv;
    attn[1] = e1 * inv;
  }
}

// ------- pool with layer-2 combine fused (PCH=16 -> 3125 blocks, 1 wave each) -------
__global__ void pool_fused_kernel(const unsigned short* __restrict__ st0,
                                  const unsigned short* __restrict__ st1,
                                  const float* __restrict__ attn,
                                  const int* __restrict__ batch,
                                  float* __restrict__ psum, int n) {
  int c0 = blockIdx.x * PCH;
  if (c0 >= n) return;
  int lane = threadIdx.x;  // 64; 2 features each
  float a0 = attn[0], a1 = attn[1];
  int end = min(c0 + PCH, n);
  int g_cur = batch[c0];
  float acc0 = 0.f, acc1 = 0.f;
  for (int nn = c0; nn < end; ++nn) {
    int g = batch[nn];
    if (g != g_cur) {
      atomicAdd(&psum[g_cur * 128 + lane * 2], acc0);
      atomicAdd(&psum[g_cur * 128 + lane * 2 + 1], acc1);
      acc0 = acc1 = 0.f;
      g_cur = g;
    }
    unsigned int u0 = *(const unsigned int*)&st0[(size_t)nn * 128 + lane * 2];
    unsigned int u1 = *(const unsigned int*)&st1[(size_t)nn * 128 + lane * 2];
    acc0 += bf2f(f2bf(a0 * bf2f((unsigned short)(u0 & 0xffff)) +
                      a1 * bf2f((unsigned short)(u1 & 0xffff))));
    acc1 += bf2f(f2bf(a0 * bf2f((unsigned short)(u0 >> 16)) +
                      a1 * bf2f((unsigned short)(u1 >> 16))));
  }
  atomicAdd(&psum[g_cur * 128 + lane * 2], acc0);
  atomicAdd(&psum[g_cur * 128 + lane * 2 + 1], acc1);
}

__device__ __forceinline__ int lower_bound_i(const int* a, int n, int key) {
  int lo = 0, hi = n;
  while (lo < hi) {
    int mid = (lo + hi) >> 1;
    if (a[mid] < key) lo = mid + 1; else hi = mid;
  }
  return lo;
}

// ------- fused pool-final + MLP head: G blocks x 128 threads -------
__global__ void poolhead_kernel(const float* __restrict__ psum, const int* __restrict__ batch,
                                int n, const float* __restrict__ d1w,
                                const float* __restrict__ d1b, const float* __restrict__ gamma,
                                const float* __restrict__ beta, const float* __restrict__ mean,
                                const float* __restrict__ var, const float* __restrict__ d2w,
                                const float* __restrict__ d2b, float* __restrict__ out) {
  __shared__ float pool_sh[128];
  int g = blockIdx.x;
  int f = threadIdx.x;  // 128
  int lo = lower_bound_i(batch, n, g);
  int hi = lower_bound_i(batch, n, g + 1);
  float cnt = fmaxf((float)(hi - lo), 1.f);
  pool_sh[f] = psum[g * 128 + f] / cnt;
  __syncthreads();
  if (f < 64) {
    float acc = d1b[f];
#pragma unroll 8
    for (int k = 0; k < 128; ++k) acc += pool_sh[k] * d1w[k * 64 + f];
    float z = (acc - mean[f]) / sqrtf(var[f] + 1e-5f) * gamma[f] + beta[f];
    z = (z >= 0.f) ? z : 0.1f * z;
    float t = z * d2w[f];
#pragma unroll
    for (int off = 32; off > 0; off >>= 1) t += __shfl_down(t, off, 64);
    if (f == 0) out[g] = t + d2b[0];
  }
}

// =====================================================================
extern "C" void kernel_launch(void* const* d_in, const int* in_sizes, int n_in,
                              void* d_out, int out_size, void* d_ws, size_t ws_size,
                              hipStream_t stream) {
  const float* x      = (const float*)d_in[0];
  const int* ei0      = (const int*)d_in[1];
  const int* ei1      = (const int*)d_in[2];
  const int* batch    = (const int*)d_in[3];
  const float* p1w    = (const float*)d_in[4];
  const float* p1b    = (const float*)d_in[5];
  const float* as1r0  = (const float*)d_in[6];
  const float* ad1r0  = (const float*)d_in[7];
  const float* as1r1  = (const float*)d_in[8];
  const float* ad1r1  = (const float*)d_in[9];
  const float* kl1w   = (const float*)d_in[10];
  const float* kl1b   = (const float*)d_in[11];
  const float* q1     = (const float*)d_in[12];
  const float* p2w    = (const float*)d_in[13];
  const float* p2b    = (const float*)d_in[14];
  const float* as2r0  = (const float*)d_in[15];
  const float* ad2r0  = (const float*)d_in[16];
  const float* as2r1  = (const float*)d_in[17];
  const float* ad2r1  = (const float*)d_in[18];
  const float* kl2w   = (const float*)d_in[19];
  const float* kl2b   = (const float*)d_in[20];
  const float* q2     = (const float*)d_in[21];
  const float* d1w    = (const float*)d_in[22];
  const float* d1b    = (const float*)d_in[23];
  const float* bng    = (const float*)d_in[24];
  const float* bnb    = (const float*)d_in[25];
  const float* bnm    = (const float*)d_in[26];
  const float* bnv    = (const float*)d_in[27];
  const float* d2w    = (const float*)d_in[28];
  const float* d2b    = (const float*)d_in[29];
  float* out = (float*)d_out;

  const int N = in_sizes[3];       // 50000
  const int E = in_sizes[1] / 2;   // 400000
  const int G = 64;

  char* p = (char*)d_ws;
  auto alloc = [&](size_t bytes) -> void* {
    void* r = (void*)p;
    p += (bytes + 255) & ~(size_t)255;
    return r;
  };
  int* rp0    = (int*)alloc((N + 1) * sizeof(int));
  int* rp1    = (int*)alloc((N + 1) * sizeof(int));
  int* cs0    = (int*)alloc(E * sizeof(int));        // src per CSR slot
  int* cs1    = (int*)alloc(E * sizeof(int));
  int* deg    = (int*)alloc(2 * (size_t)N * sizeof(int));   // deg+cur: one memset
  int* cur    = (int*)alloc(2 * (size_t)N * sizeof(int));
  int* incl   = (int*)alloc(2 * (size_t)N * sizeof(int));
  int* bsum   = (int*)alloc(512 * sizeof(int));
  unsigned short* h_bf  = (unsigned short*)alloc((size_t)N * 256 * 2);
  unsigned short* st0   = (unsigned short*)alloc((size_t)N * 256 * 2);
  unsigned short* st1   = (unsigned short*)alloc((size_t)N * 256 * 2);
  unsigned short* h2_bf = (unsigned short*)alloc((size_t)N * 128 * 2);
  unsigned short* p1wt  = (unsigned short*)alloc(128 * 256 * 2);
  unsigned short* p2wt  = (unsigned short*)alloc(256 * 128 * 2);
  unsigned short* k1wt  = (unsigned short*)alloc(256 * 256 * 2);
  unsigned short* k2wt  = (unsigned short*)alloc(128 * 128 * 2);
  float* s0     = (float*)alloc((size_t)N * NHEAD * sizeof(float));
  float* d0     = (float*)alloc((size_t)N * NHEAD * sizeof(float));
  float* s1     = (float*)alloc((size_t)N * NHEAD * sizeof(float));
  float* d1     = (float*)alloc((size_t)N * NHEAD * sizeof(float));
  float* wslots = (float*)alloc((size_t)NSLOT * SLOT_STRIDE * sizeof(float));
  float* attn1  = (float*)alloc(2 * sizeof(float));
  float* attn2  = (float*)alloc(2 * sizeof(float));
  float* psum   = (float*)alloc((size_t)G * 128 * sizeof(float));

  // ---- 1: zero deg+cur (contiguous allocs -> single memset) ----
  size_t zlen = (size_t)((char*)cur - (char*)deg) + 2 * (size_t)N * sizeof(int);
  hipMemsetAsync(deg, 0, zlen, stream);

  // ---- 2: weight fragment-pack fused with dst histogram ----
  int wblk = 576;  // 147456 / 256
  int e2blk = (2 * E + 255) / 256;
  wtrans_hist_kernel<<<wblk + e2blk, 256, 0, stream>>>(
      p1w, p2w, kl1w, kl2w, p1wt, p2wt, k1wt, k2wt, ei0, ei1, E, deg, N, wblk);

  // ---- 3-6: scan + scatter ----
  int nb = (N + 255) / 256;
  scan_local2_kernel<<<2 * nb, 256, 0, stream>>>(deg, incl, bsum, N, nb);
  scan_bsum2_kernel<<<2, 256, 0, stream>>>(bsum, nb);
  scan_fix2_kernel<<<2 * nb, 256, 0, stream>>>(incl, deg, bsum, rp0, rp1, N, nb, E);
  scatter2_kernel<<<e2blk, 256, 0, stream>>>(ei0, ei1, E, rp0, rp1, cur, cs0, cs1, N);

  int gblk = (N + 63) / 64;
  int nblk4 = (N + 3) / 4;

  // ================= layer 1: 128 -> 256, D=64 =================
  mfma_gemm_proj<128, 256, 1, 64><<<gblk, 256, 0, stream>>>(
      x, nullptr, nullptr, nullptr, p1wt, p1b, h_bf,
      as1r0, ad1r0, as1r1, ad1r1, s0, d0, s1, d1, N);
  message2_kernel<256, 64><<<2 * nblk4, 256, 0, stream>>>(
      h_bf, cs0, rp0, s0, d0, st0, cs1, rp1, s1, d1, st1, wslots, N, nblk4);
  mfma_gemm_tanh2<256, 256><<<2 * gblk, 256, 0, stream>>>(
      st0, st1, k1wt, kl1b, wslots, N, gblk);
  attn_kernel<256, false><<<1, 256, 0, stream>>>(wslots, q1, attn1, 1.0f / (float)N,
                                                 nullptr, 0);

  // ================= layer 2: 256 -> 128, D=32 =================
  mfma_gemm_proj<256, 128, 2, 32><<<gblk, 256, 0, stream>>>(
      nullptr, st0, st1, attn1, p2wt, p2b, h2_bf,
      as2r0, ad2r0, as2r1, ad2r1, s0, d0, s1, d1, N);
  message2_kernel<128, 32><<<2 * nblk4, 256, 0, stream>>>(
      h2_bf, cs0, rp0, s0, d0, st0, cs1, rp1, s1, d1, st1, wslots, N, nblk4);
  mfma_gemm_tanh2<128, 128><<<2 * gblk, 256, 0, stream>>>(
      st0, st1, k2wt, kl2b, wslots, N, gblk);
  attn_kernel<128, true><<<1, 128, 0, stream>>>(wslots, q2, attn2, 1.0f / (float)N,
                                                psum, G * 128);

  // ---- pool (combine fused) + fused final/head ----
  int pblk = (N + PCH - 1) / PCH;
  pool_fused_kernel<<<pblk, 64, 0, stream>>>(st0, st1, attn2, batch, psum, N);
  poolhead_kernel<<<G, 128, 0, stream>>>(psum, batch, N, d1w, d1b, bng, bnb, bnm, bnv,
                                         d2w, d2b, out);
}